// Round 16
// baseline (411.974 us; speedup 1.0000x reference)
//
#include <hip/hip_runtime.h>
#include <math.h>

typedef _Float16 f16;
typedef _Float16 f16x4 __attribute__((ext_vector_type(4)));
typedef _Float16 f16x8 __attribute__((ext_vector_type(8)));
typedef float f32x4 __attribute__((ext_vector_type(4)));
typedef float f32x16 __attribute__((ext_vector_type(16)));

#define MFMA32_F16 __builtin_amdgcn_mfma_f32_32x32x16_f16

namespace {
constexpr int kL = 4096;   // faces (queries)
constexpr int kS = 8192;   // edges (keys/values)
constexpr int kD = 256;    // embed dim
constexpr int kH = 2;      // heads
constexpr int kDH = 128;   // head dim
constexpr int kNL = 4;     // layers
constexpr int kNS = 8;     // S-dim splits in dense attention
constexpr float kScale = 0.08838834764831845f;  // 1/sqrt(128)
}

// ---------- fused f32->f16 conversion of all inputs (one dispatch) ----------
__global__ __launch_bounds__(256) void cvt_all_k(
    const float* __restrict__ edge, const float* __restrict__ face,
    const float* __restrict__ inw, const float* __restrict__ outw,
    f16* __restrict__ e16, f16* __restrict__ xa,
    f16* __restrict__ win16, f16* __restrict__ wout16) {
  for (int i = blockIdx.x * 256 + threadIdx.x; i < 1048576; i += 1024 * 256) {
    const float* src;
    f16* dst;
    int off;
    if (i < 524288) { src = edge; dst = e16; off = i; }
    else if (i < 786432) { src = face; dst = xa; off = i - 524288; }
    else if (i < 983040) { src = inw; dst = win16; off = i - 786432; }
    else { src = outw; dst = wout16; off = i - 983040; }
    float4 v = *(const float4*)(src + 4 * (size_t)off);
    f16x4 h;
    h[0] = (f16)v.x; h[1] = (f16)v.y; h[2] = (f16)v.z; h[3] = (f16)v.w;
    *(f16x4*)(dst + 4 * (size_t)off) = h;
  }
}

// Detect on-device element widths of loop (int32/int64) and mask (1/4/8 B).
__global__ __launch_bounds__(256) void detect_k(const unsigned int* __restrict__ loopw,
                                                const unsigned char* __restrict__ maskb,
                                                int* __restrict__ flags) {
  __shared__ unsigned int s[3];
  if (threadIdx.x < 3) s[threadIdx.x] = 0;
  __syncthreads();
  unsigned int orodd = 0;
  for (int i = 1 + 2 * threadIdx.x; i < 2048; i += 512) orodd |= loopw[i];
  unsigned int nz1 = 0, nz4 = 0;
  for (int i = threadIdx.x; i < 512; i += 256) {
    unsigned char b = maskb[i];
    if ((i & 3) != 0) nz1 |= b;
    if ((i & 7) == 4) nz4 |= b;
  }
  atomicOr(&s[0], orodd);
  atomicOr(&s[1], nz1);
  atomicOr(&s[2], nz4);
  __syncthreads();
  if (threadIdx.x == 0) {
    flags[0] = (s[0] == 0) ? 2 : 1;
    flags[1] = s[1] ? 1 : (s[2] ? 4 : 8);
  }
}

// ---------- weight composition: wqo_l = wq_l . wo_{l-1}, b' = wq_l.bo + bq --
__global__ __launch_bounds__(256) void compose_k(
    const float* __restrict__ inw, const float* __restrict__ inb,
    const float* __restrict__ outw, const float* __restrict__ outb,
    f16* __restrict__ wqo, float* __restrict__ bprime) {
  const int lc = blockIdx.y;  // 0..2 -> layer l = lc+1
  const int i = blockIdx.x;   // output row
  const int j = threadIdx.x;  // output col
  const int l = lc + 1;
  const float* wq = inw + (size_t)l * 3 * kD * kD;
  const float* wo = outw + (size_t)lc * kD * kD;
  float acc = 0.0f;
  for (int k = 0; k < kD; ++k)
    acc += wq[i * kD + k] * wo[k * kD + j];
  wqo[((size_t)lc * kD + i) * kD + j] = (f16)acc;

  float t = wq[i * kD + j] * outb[lc * kD + j];
  __shared__ float red[4];
#pragma unroll
  for (int m = 1; m < 64; m <<= 1) t += __shfl_xor(t, m);
  if ((threadIdx.x & 63) == 0) red[threadIdx.x >> 6] = t;
  __syncthreads();
  if (threadIdx.x == 0)
    bprime[lc * kD + i] = red[0] + red[1] + red[2] + red[3] + inb[l * 3 * kD + i];
}

// ---------- helpers: pkh / pswap / verified 16-f32 -> 2x f16x8 epilogue ----
__device__ __forceinline__ unsigned pkh(float a, float b) {
  auto h2 = __builtin_amdgcn_cvt_pkrtz(a, b);
  return __builtin_bit_cast(unsigned, h2);
}
__device__ __forceinline__ void pswap(unsigned a, unsigned b, unsigned& x,
                                      unsigned& y) {
  typedef int i32x2 __attribute__((ext_vector_type(2)));
  i32x2 rr = __builtin_amdgcn_permlane32_swap((int)a, (int)b, false, false);
  x = (unsigned)rr[0];
  y = (unsigned)rr[1];
}
__device__ __forceinline__ f16x8 build_pfrag(float p0, float p1, float p2,
                                             float p3, float p4, float p5,
                                             float p6, float p7) {
  unsigned a0 = pkh(p0, p1), b0 = pkh(p4, p5);
  unsigned a1 = pkh(p2, p3), b1 = pkh(p6, p7);
  unsigned w0, w1, w2, w3;
  pswap(a0, b0, w0, w2);
  pswap(a1, b1, w1, w3);
  union { unsigned u[4]; f16x8 v; } r;
  r.u[0] = w0; r.u[1] = w1; r.u[2] = w2; r.u[3] = w3;
  return r.v;
}
// Store a 32x32 C-fragment row (f32x16, col=lane&31, row=(i&3)+8*(i>>2)+4*hi)
// as two f16x8 stores at base+hi*8 and base+16+hi*8 (round-10/11-verified).
__device__ __forceinline__ void store16(const f32x16& a, f16* base, int hi) {
  unsigned u01 = pkh(a[0], a[1]), u23 = pkh(a[2], a[3]);
  unsigned u89 = pkh(a[4], a[5]), uab = pkh(a[6], a[7]);
  unsigned w0, w1, w2, w3;
  pswap(u01, u89, w0, w2);
  pswap(u23, uab, w1, w3);
  union { unsigned u[4]; f16x8 v; } r1;
  r1.u[0] = w0; r1.u[1] = w1; r1.u[2] = w2; r1.u[3] = w3;
  *(f16x8*)(base + hi * 8) = r1.v;
  unsigned v01 = pkh(a[8], a[9]), v23 = pkh(a[10], a[11]);
  unsigned v89 = pkh(a[12], a[13]), vab = pkh(a[14], a[15]);
  unsigned x0, x1, x2, x3;
  pswap(v01, v89, x0, x2);
  pswap(v23, vab, x1, x3);
  union { unsigned u[4]; f16x8 v; } r2;
  r2.u[0] = x0; r2.u[1] = x1; r2.u[2] = x2; r2.u[3] = x3;
  *(f16x8*)(base + 16 + hi * 8) = r2.v;
}

// ---------- generic 32x32-MFMA GEMM: C = X @ W^T + bias (M rows, N=K=256) --
// MFMA(W-rows -> regs, X-rows -> lane): lane la = output ROW -> vectorized
// row stores via store16 (replaces 16 scalar stores of the old 16x16 form).
__global__ __launch_bounds__(256) void gemm32_k(
    const f16* __restrict__ X, const f16* __restrict__ W,
    const float* __restrict__ bias, f16* __restrict__ C16,
    float* __restrict__ C32) {
  const int lane = threadIdx.x & 63, wid = threadIdx.x >> 6;
  const int la = lane & 31, hi = lane >> 5;
  const int wm = wid & 1, wn = wid >> 1;
  const int m0 = blockIdx.x * 64 + wm * 32;
  const int n0 = blockIdx.y * 64 + wn * 32;
  const f16* wp = W + (size_t)(n0 + la) * kD + hi * 8;
  const f16* xp = X + (size_t)(m0 + la) * kD + hi * 8;
  f32x16 acc = {};
  f16x8 wa = *(const f16x8*)wp, xb = *(const f16x8*)xp;
#pragma unroll
  for (int t = 0; t < 15; ++t) {
    f16x8 wnx = *(const f16x8*)(wp + (t + 1) * 16);
    f16x8 xnx = *(const f16x8*)(xp + (t + 1) * 16);
    acc = MFMA32_F16(wa, xb, acc, 0, 0, 0);
    wa = wnx;
    xb = xnx;
  }
  acc = MFMA32_F16(wa, xb, acc, 0, 0, 0);
#pragma unroll
  for (int i = 0; i < 16; ++i)
    acc[i] += bias[n0 + (i & 3) + 8 * (i >> 2) + 4 * hi];
  if (C16) store16(acc, C16 + (size_t)(m0 + la) * kD + n0, hi);
  if (C32) {
    float* row = C32 + (size_t)(m0 + la) * kD + n0;
    float4 f0 = {acc[0], acc[1], acc[2], acc[3]};
    float4 f1 = {acc[4], acc[5], acc[6], acc[7]};
    float4 f2 = {acc[8], acc[9], acc[10], acc[11]};
    float4 f3 = {acc[12], acc[13], acc[14], acc[15]};
    *(float4*)(row + 4 * hi) = f0;
    *(float4*)(row + 8 + 4 * hi) = f1;
    *(float4*)(row + 16 + 4 * hi) = f2;
    *(float4*)(row + 24 + 4 * hi) = f3;
  }
}

// ---------- all-layer K/V projection, 32x32 MFMA, vectorized stores -------
// K-blocks: one acc (lane=edge row) -> k16. V-blocks: the same loaded regs
// feed BOTH operand orders -> acc_rm (lane=edge) for v16 and acc_tr
// (lane=outdim) for vt16 -- no LDS bounce, no barrier.
__global__ __launch_bounds__(256) void kvall2_k(
    const f16* __restrict__ e16, const f16* __restrict__ win16,
    const float* __restrict__ inb,
    f16* __restrict__ k16all, f16* __restrict__ vt16all,
    f16* __restrict__ v16all) {
  const int lane = threadIdx.x & 63, wid = threadIdx.x >> 6;
  const int la = lane & 31, hi = lane >> 5;
  const int wm = wid & 1, wn = wid >> 1;
  const int bid = blockIdx.x;
  const int l = bid >> 10;
  const int tt = bid & 1023;
  const int bx = tt & 127, by = tt >> 7;  // by 0-3: K cols, 4-7: V cols
  const int m0 = bx * 64 + wm * 32;
  const int nb = by * 64 + wn * 32;  // 0..511 within [wk;wv]
  const f16* W = win16 + (size_t)l * 3 * kD * kD + (size_t)kD * kD;
  const float* bias = inb + (size_t)l * 3 * kD + kD;
  const f16* wp = W + (size_t)(nb + la) * kD + hi * 8;
  const f16* xp = e16 + (size_t)(m0 + la) * kD + hi * 8;

  if (by < 4) {
    f32x16 acc = {};
    f16x8 wa = *(const f16x8*)wp, xb = *(const f16x8*)xp;
#pragma unroll
    for (int t = 0; t < 15; ++t) {
      f16x8 wnx = *(const f16x8*)(wp + (t + 1) * 16);
      f16x8 xnx = *(const f16x8*)(xp + (t + 1) * 16);
      acc = MFMA32_F16(wa, xb, acc, 0, 0, 0);
      wa = wnx;
      xb = xnx;
    }
    acc = MFMA32_F16(wa, xb, acc, 0, 0, 0);
#pragma unroll
    for (int i = 0; i < 16; ++i)
      acc[i] += bias[nb + (i & 3) + 8 * (i >> 2) + 4 * hi];
    store16(acc, k16all + (size_t)l * kS * kD + (size_t)(m0 + la) * kD + nb,
            hi);
  } else {
    f32x16 arm = {}, atr = {};
    f16x8 wa = *(const f16x8*)wp, xb = *(const f16x8*)xp;
#pragma unroll
    for (int t = 0; t < 15; ++t) {
      f16x8 wnx = *(const f16x8*)(wp + (t + 1) * 16);
      f16x8 xnx = *(const f16x8*)(xp + (t + 1) * 16);
      arm = MFMA32_F16(wa, xb, arm, 0, 0, 0);
      atr = MFMA32_F16(xb, wa, atr, 0, 0, 0);
      wa = wnx;
      xb = xnx;
    }
    arm = MFMA32_F16(wa, xb, arm, 0, 0, 0);
    atr = MFMA32_F16(xb, wa, atr, 0, 0, 0);
    const int dv0 = nb - 256;
#pragma unroll
    for (int i = 0; i < 16; ++i)
      arm[i] += bias[nb + (i & 3) + 8 * (i >> 2) + 4 * hi];
    store16(arm, v16all + (size_t)l * kS * kD + (size_t)(m0 + la) * kD + dv0,
            hi);
    const float bv = bias[nb + la];
#pragma unroll
    for (int i = 0; i < 16; ++i) atr[i] += bv;
    store16(atr, vt16all + (size_t)l * kS * kD + (size_t)(dv0 + la) * kS + m0,
            hi);
  }
}

// ---------- dense attention: round-11-verified attn_dense7 (45.6 us) ------
__global__ __launch_bounds__(256, 2) void attn_dense7_k(
    const f16* __restrict__ Q, const f16* __restrict__ Km,
    const f16* __restrict__ Vt,
    f16* __restrict__ numOut, float* __restrict__ denOut) {
  __shared__ __align__(16) f16 Kl[2][64 * 128];  // [key][d], XOR-swizzled
  __shared__ __align__(16) f16 Vl[2][128 * 64];  // [d][key], XOR-swizzled
  const int tid = threadIdx.x;
  const int lane = tid & 63, wid = tid >> 6;
  const int la = lane & 31, hi = lane >> 5;
  const int id = blockIdx.x;
  const int grp = id & 15;
  const int h = grp & 1;
  const int z = grp >> 1;
  const int bx = id >> 4;
  const int q0w = bx * 128 + wid * 32;
  const int sb0 = z * (kS / kNS);
  const int nt = (kS / kNS) / 64;  // 16

  f16x8 qb[8];
#pragma unroll
  for (int kk = 0; kk < 8; ++kk)
    qb[kk] = *(const f16x8*)(Q + (size_t)(q0w + la) * kD + h * kDH + kk * 16 +
                             hi * 8);

  int kSrc[4], kDst[4], vSrc[4], vDst[4];
#pragma unroll
  for (int p = 0; p < 4; ++p) {
    int m = wid * 16 + p * 4 + (lane >> 4);
    int s = lane & 15;
    kSrc[p] = (sb0 + m) * kD + h * kDH + 8 * (s ^ (m & 7));
    kDst[p] = m * 128 + 8 * s;
    int cv = p * 256 + tid;
    int d = cv >> 3, sv = cv & 7;
    vSrc[p] = (h * kDH + d) * kS + sb0 + 8 * (sv ^ (d & 7));
    vDst[p] = d * 64 + 8 * sv;
  }

  f32x16 o0 = {}, o1 = {}, o2 = {}, o3 = {};
  float den = 0.0f;
  f16x8 kst[4], vst[4];

#pragma unroll
  for (int p = 0; p < 4; ++p) {
    kst[p] = *(const f16x8*)(Km + kSrc[p]);
    vst[p] = *(const f16x8*)(Vt + vSrc[p]);
  }
#pragma unroll
  for (int p = 0; p < 4; ++p) {
    *(f16x8*)&Kl[0][kDst[p]] = kst[p];
    *(f16x8*)&Vl[0][vDst[p]] = vst[p];
  }
  __syncthreads();

  for (int t = 0; t < nt; ++t) {
    const int cur = t & 1;
    if (t + 1 < nt) {
#pragma unroll
      for (int p = 0; p < 4; ++p) {
        kst[p] = *(const f16x8*)(Km + kSrc[p] + (t + 1) * 64 * kD);
        vst[p] = *(const f16x8*)(Vt + vSrc[p] + (t + 1) * 64);
      }
    }

    f32x16 st0 = {}, st1 = {};
    __builtin_amdgcn_s_setprio(1);
#pragma unroll
    for (int kk = 0; kk < 8; ++kk) {
      int sl = 8 * ((kk * 2 + hi) ^ (la & 7));
      f16x8 k0 = *(const f16x8*)&Kl[cur][la * 128 + sl];
      f16x8 k1 = *(const f16x8*)&Kl[cur][(32 + la) * 128 + sl];
      st0 = MFMA32_F16(k0, qb[kk], st0, 0, 0, 0);
      st1 = MFMA32_F16(k1, qb[kk], st1, 0, 0, 0);
    }
    __builtin_amdgcn_s_setprio(0);

    f32x16 pe0, pe1;
#pragma unroll
    for (int i = 0; i < 16; ++i) {
      pe0[i] = __expf(st0[i] * kScale);
      pe1[i] = __expf(st1[i] * kScale);
    }
#pragma unroll
    for (int i = 0; i < 16; ++i) den += pe0[i] + pe1[i];

    f16x8 pf[4];
    pf[0] = build_pfrag(pe0[0], pe0[1], pe0[2], pe0[3], pe0[4], pe0[5], pe0[6], pe0[7]);
    pf[1] = build_pfrag(pe0[8], pe0[9], pe0[10], pe0[11], pe0[12], pe0[13], pe0[14], pe0[15]);
    pf[2] = build_pfrag(pe1[0], pe1[1], pe1[2], pe1[3], pe1[4], pe1[5], pe1[6], pe1[7]);
    pf[3] = build_pfrag(pe1[8], pe1[9], pe1[10], pe1[11], pe1[12], pe1[13], pe1[14], pe1[15]);

    __builtin_amdgcn_s_setprio(1);
#pragma unroll
    for (int dt = 0; dt < 4; ++dt) {
      int d = dt * 32 + la;
      f32x16* op = (dt == 0) ? &o0 : (dt == 1) ? &o1 : (dt == 2) ? &o2 : &o3;
#pragma unroll
      for (int ks = 0; ks < 4; ++ks) {
        f16x8 vf = *(const f16x8*)&Vl[cur][d * 64 + 8 * ((ks * 2 + hi) ^ (d & 7))];
        *op = MFMA32_F16(vf, pf[ks], *op, 0, 0, 0);
      }
    }
    __builtin_amdgcn_s_setprio(0);

    if (t + 1 < nt) {
      const int nxt = cur ^ 1;
#pragma unroll
      for (int p = 0; p < 4; ++p) {
        *(f16x8*)&Kl[nxt][kDst[p]] = kst[p];
        *(f16x8*)&Vl[nxt][vDst[p]] = vst[p];
      }
      __syncthreads();
    }
  }

  const size_t nbase = ((size_t)z * kH + h) * kL + q0w;
  const size_t rowb = (nbase + la) * kDH;
#pragma unroll
  for (int dt = 0; dt < 4; ++dt) {
    const f32x16* op = (dt == 0) ? &o0 : (dt == 1) ? &o1 : (dt == 2) ? &o2 : &o3;
    store16(*op, numOut + rowb + dt * 32, hi);
  }
  float dq = den + __shfl_xor(den, 32);
  if (lane < 32)
    denOut[((size_t)z * kH + h) * kL + q0w + lane] = dq;
}

// ---------- fused correction + combine (round-11-verified serial form) ----
__global__ __launch_bounds__(256) void corrcomb_k(
    const unsigned int* __restrict__ loopw, const unsigned char* __restrict__ maskb,
    const int* __restrict__ flags,
    const f16* __restrict__ Q, const f16* __restrict__ Km,
    const f16* __restrict__ V,
    const f16* __restrict__ numb, const float* __restrict__ denb,
    f16* __restrict__ out16) {
  __shared__ float cvL[4][128];
  __shared__ float csL[4];
  const int lane = threadIdx.x & 63;
  const int wid = threadIdx.x >> 6;
  const int w = blockIdx.x * 4 + wid;
  const int f = w >> 1, h = w & 1;
  const int lstride = flags[0];
  const int mstride = flags[1];

  int idx = -1, valid = 0;
  if (lane < 32) {
    idx = (int)loopw[(size_t)(f * 32 + lane) * lstride];
    valid = maskb[(size_t)f * mstride] ? 1 : 0;
  }
#pragma unroll
  for (int j = 0; j < 32; ++j) {
    int oidx = __shfl(idx, j);
    if (lane < 32 && j < lane && oidx == idx) valid = 0;
  }

  const size_t qb = (size_t)f * kD + h * kDH + 2 * lane;
  const float qa = (float)Q[qb];
  const float qbv = (float)Q[qb + 1];
  float s0 = 0.0f, cv0 = 0.0f, cv1 = 0.0f;
  for (int e = 0; e < 32; ++e) {
    int ei = __shfl(idx, e);
    int ev = __shfl(valid, e);
    if (!ev) continue;
    size_t kb = (size_t)ei * kD + h * kDH + 2 * lane;
    float part = qa * (float)Km[kb] + qbv * (float)Km[kb + 1];
#pragma unroll
    for (int m = 1; m < 64; m <<= 1) part += __shfl_xor(part, m);
    float pe = __expf(part * kScale);
    s0 += pe;
    cv0 += pe * (float)V[kb];
    cv1 += pe * (float)V[kb + 1];
  }
  cvL[wid][2 * lane] = cv0;
  cvL[wid][2 * lane + 1] = cv1;
  if (lane == 0) csL[wid] = s0;
  __syncthreads();

#pragma unroll
  for (int e = 0; e < 2; ++e) {
    int idx2 = e * 256 + threadIdx.x;
    int floc = idx2 >> 8;
    int c = idx2 & 255;
    int h2 = c >> 7;
    int d = c & 127;
    int widx = floc * 2 + h2;
    int fabs_ = blockIdx.x * 2 + floc;
    float n = -cvL[widx][d];
    float dn = -csL[widx];
#pragma unroll
    for (int z = 0; z < kNS; ++z) {
      n += (float)numb[((size_t)(z * kH + h2) * kL + fabs_) * kDH + d];
      dn += denb[((size_t)z * kH + h2) * kL + fabs_];
    }
    out16[(size_t)fabs_ * kD + h2 * kDH + d] = (f16)(n / dn);
  }
}

extern "C" void kernel_launch(void* const* d_in, const int* in_sizes, int n_in,
                              void* d_out, int out_size, void* d_ws, size_t ws_size,
                              hipStream_t stream) {
  const unsigned int* loopw = (const unsigned int*)d_in[0];
  const unsigned char* fmask = (const unsigned char*)d_in[1];
  const float* edge = (const float*)d_in[2];
  const float* face = (const float*)d_in[3];
  const float* inw = (const float*)d_in[4];
  const float* inb = (const float*)d_in[5];
  const float* outw = (const float*)d_in[6];
  const float* outb = (const float*)d_in[7];
  float* out = (float*)d_out;

  char* p = (char*)d_ws;
  auto alloc = [&](size_t bytes) {
    char* q = p;
    p += (bytes + 255) & ~(size_t)255;
    return q;
  };
  int* flags = (int*)alloc(256);
  f16* e16 = (f16*)alloc((size_t)kS * kD * 2);
  f16* win16 = (f16*)alloc((size_t)kNL * 3 * kD * kD * 2);
  f16* wout16 = (f16*)alloc((size_t)kNL * kD * kD * 2);
  f16* xa = (f16*)alloc((size_t)kL * kD * 2);
  f16* q16 = (f16*)alloc((size_t)kL * kD * 2);
  f16* ao16 = (f16*)alloc((size_t)kL * kD * 2);
  f16* wqo = (f16*)alloc((size_t)3 * kD * kD * 2);
  float* bprime = (float*)alloc((size_t)3 * kD * 4);
  f16* k16all = (f16*)alloc((size_t)kNL * kS * kD * 2);
  f16* vt16all = (f16*)alloc((size_t)kNL * kS * kD * 2);
  f16* v16all = (f16*)alloc((size_t)kNL * kS * kD * 2);
  f16* numb = (f16*)alloc((size_t)kNS * kH * kL * kDH * 2);
  float* denb = (float*)alloc((size_t)kNS * kH * kL * 4);

  detect_k<<<1, 256, 0, stream>>>(loopw, fmask, flags);
  cvt_all_k<<<1024, 256, 0, stream>>>(edge, face, inw, outw, e16, xa, win16,
                                      wout16);
  compose_k<<<dim3(256, 3), 256, 0, stream>>>(inw, inb, outw, outb, wqo,
                                              bprime);
  kvall2_k<<<4096, 256, 0, stream>>>(e16, win16, inb, k16all, vt16all, v16all);

  for (int l = 0; l < kNL; ++l) {
    const f16* kl = k16all + (size_t)l * kS * kD;
    const f16* vtl = vt16all + (size_t)l * kS * kD;
    const f16* vl = v16all + (size_t)l * kS * kD;
    if (l == 0) {
      gemm32_k<<<dim3(64, 4), 256, 0, stream>>>(xa, win16, inb, q16, nullptr);
    } else {
      gemm32_k<<<dim3(64, 4), 256, 0, stream>>>(
          ao16, wqo + (size_t)(l - 1) * kD * kD, bprime + (l - 1) * kD, q16,
          nullptr);
    }
    attn_dense7_k<<<512, 256, 0, stream>>>(q16, kl, vtl, numb, denb);
    corrcomb_k<<<kL / 2, 256, 0, stream>>>(loopw, fmask, flags, q16, kl, vl,
                                           numb, denb, ao16);
  }
  // final out-projection (only layer 3's survives composition), f32 output
  gemm32_k<<<dim3(64, 4), 256, 0, stream>>>(
      ao16, wout16 + (size_t)3 * kD * kD, outb + 3 * kD, nullptr, out);
}

// Round 17
// 409.830 us; speedup vs baseline: 1.0052x; 1.0052x over previous
//
#include <hip/hip_runtime.h>
#include <math.h>

typedef _Float16 f16;
typedef _Float16 f16x4 __attribute__((ext_vector_type(4)));
typedef _Float16 f16x8 __attribute__((ext_vector_type(8)));
typedef float f32x4 __attribute__((ext_vector_type(4)));
typedef float f32x16 __attribute__((ext_vector_type(16)));

#define MFMA32_F16 __builtin_amdgcn_mfma_f32_32x32x16_f16

namespace {
constexpr int kL = 4096;   // faces (queries)
constexpr int kS = 8192;   // edges (keys/values)
constexpr int kD = 256;    // embed dim
constexpr int kH = 2;      // heads
constexpr int kDH = 128;   // head dim
constexpr int kNL = 4;     // layers
constexpr int kNS = 8;     // S-dim splits in dense attention
constexpr float kScale = 0.08838834764831845f;  // 1/sqrt(128)
}

// ---------- fused f32->f16 conversion of all inputs (one dispatch) ----------
__global__ __launch_bounds__(256) void cvt_all_k(
    const float* __restrict__ edge, const float* __restrict__ face,
    const float* __restrict__ inw, const float* __restrict__ outw,
    f16* __restrict__ e16, f16* __restrict__ xa,
    f16* __restrict__ win16, f16* __restrict__ wout16) {
  for (int i = blockIdx.x * 256 + threadIdx.x; i < 1048576; i += 1024 * 256) {
    const float* src;
    f16* dst;
    int off;
    if (i < 524288) { src = edge; dst = e16; off = i; }
    else if (i < 786432) { src = face; dst = xa; off = i - 524288; }
    else if (i < 983040) { src = inw; dst = win16; off = i - 786432; }
    else { src = outw; dst = wout16; off = i - 983040; }
    float4 v = *(const float4*)(src + 4 * (size_t)off);
    f16x4 h;
    h[0] = (f16)v.x; h[1] = (f16)v.y; h[2] = (f16)v.z; h[3] = (f16)v.w;
    *(f16x4*)(dst + 4 * (size_t)off) = h;
  }
}

// Detect on-device element widths of loop (int32/int64) and mask (1/4/8 B).
__global__ __launch_bounds__(256) void detect_k(const unsigned int* __restrict__ loopw,
                                                const unsigned char* __restrict__ maskb,
                                                int* __restrict__ flags) {
  __shared__ unsigned int s[3];
  if (threadIdx.x < 3) s[threadIdx.x] = 0;
  __syncthreads();
  unsigned int orodd = 0;
  for (int i = 1 + 2 * threadIdx.x; i < 2048; i += 512) orodd |= loopw[i];
  unsigned int nz1 = 0, nz4 = 0;
  for (int i = threadIdx.x; i < 512; i += 256) {
    unsigned char b = maskb[i];
    if ((i & 3) != 0) nz1 |= b;
    if ((i & 7) == 4) nz4 |= b;
  }
  atomicOr(&s[0], orodd);
  atomicOr(&s[1], nz1);
  atomicOr(&s[2], nz4);
  __syncthreads();
  if (threadIdx.x == 0) {
    flags[0] = (s[0] == 0) ? 2 : 1;
    flags[1] = s[1] ? 1 : (s[2] ? 4 : 8);
  }
}

// ---------- weight composition: wqo_l = wq_l . wo_{l-1}, b' = wq_l.bo + bq --
__global__ __launch_bounds__(256) void compose_k(
    const float* __restrict__ inw, const float* __restrict__ inb,
    const float* __restrict__ outw, const float* __restrict__ outb,
    f16* __restrict__ wqo, float* __restrict__ bprime) {
  const int lc = blockIdx.y;  // 0..2 -> layer l = lc+1
  const int i = blockIdx.x;   // output row
  const int j = threadIdx.x;  // output col
  const int l = lc + 1;
  const float* wq = inw + (size_t)l * 3 * kD * kD;
  const float* wo = outw + (size_t)lc * kD * kD;
  float acc = 0.0f;
  for (int k = 0; k < kD; ++k)
    acc += wq[i * kD + k] * wo[k * kD + j];
  wqo[((size_t)lc * kD + i) * kD + j] = (f16)acc;

  float t = wq[i * kD + j] * outb[lc * kD + j];
  __shared__ float red[4];
#pragma unroll
  for (int m = 1; m < 64; m <<= 1) t += __shfl_xor(t, m);
  if ((threadIdx.x & 63) == 0) red[threadIdx.x >> 6] = t;
  __syncthreads();
  if (threadIdx.x == 0)
    bprime[lc * kD + i] = red[0] + red[1] + red[2] + red[3] + inb[l * 3 * kD + i];
}

// ---------- helpers: pkh / pswap / verified 16-f32 -> 2x f16x8 epilogue ----
__device__ __forceinline__ unsigned pkh(float a, float b) {
  auto h2 = __builtin_amdgcn_cvt_pkrtz(a, b);
  return __builtin_bit_cast(unsigned, h2);
}
__device__ __forceinline__ void pswap(unsigned a, unsigned b, unsigned& x,
                                      unsigned& y) {
  typedef int i32x2 __attribute__((ext_vector_type(2)));
  i32x2 rr = __builtin_amdgcn_permlane32_swap((int)a, (int)b, false, false);
  x = (unsigned)rr[0];
  y = (unsigned)rr[1];
}
__device__ __forceinline__ f16x8 build_pfrag(float p0, float p1, float p2,
                                             float p3, float p4, float p5,
                                             float p6, float p7) {
  unsigned a0 = pkh(p0, p1), b0 = pkh(p4, p5);
  unsigned a1 = pkh(p2, p3), b1 = pkh(p6, p7);
  unsigned w0, w1, w2, w3;
  pswap(a0, b0, w0, w2);
  pswap(a1, b1, w1, w3);
  union { unsigned u[4]; f16x8 v; } r;
  r.u[0] = w0; r.u[1] = w1; r.u[2] = w2; r.u[3] = w3;
  return r.v;
}
// Store a 32x32 C-fragment row (f32x16, col=lane&31, row=(i&3)+8*(i>>2)+4*hi)
// as two f16x8 stores at base+hi*8 and base+16+hi*8 (round-10/11-verified).
__device__ __forceinline__ void store16(const f32x16& a, f16* base, int hi) {
  unsigned u01 = pkh(a[0], a[1]), u23 = pkh(a[2], a[3]);
  unsigned u89 = pkh(a[4], a[5]), uab = pkh(a[6], a[7]);
  unsigned w0, w1, w2, w3;
  pswap(u01, u89, w0, w2);
  pswap(u23, uab, w1, w3);
  union { unsigned u[4]; f16x8 v; } r1;
  r1.u[0] = w0; r1.u[1] = w1; r1.u[2] = w2; r1.u[3] = w3;
  *(f16x8*)(base + hi * 8) = r1.v;
  unsigned v01 = pkh(a[8], a[9]), v23 = pkh(a[10], a[11]);
  unsigned v89 = pkh(a[12], a[13]), vab = pkh(a[14], a[15]);
  unsigned x0, x1, x2, x3;
  pswap(v01, v89, x0, x2);
  pswap(v23, vab, x1, x3);
  union { unsigned u[4]; f16x8 v; } r2;
  r2.u[0] = x0; r2.u[1] = x1; r2.u[2] = x2; r2.u[3] = x3;
  *(f16x8*)(base + 16 + hi * 8) = r2.v;
}

// ---------- generic 32x32-MFMA GEMM: C = X @ W^T + bias (M rows, N=K=256) --
// Full-depth load prefetch: all 32 independent 16B loads issued before the
// MFMA chain -> one latency window instead of 16 (round-16 counters showed
// MfmaUtil 6.5%/VALU 4.5% = pure latency-bound with depth-1 prefetch).
__global__ __launch_bounds__(256) void gemm32_k(
    const f16* __restrict__ X, const f16* __restrict__ W,
    const float* __restrict__ bias, f16* __restrict__ C16,
    float* __restrict__ C32) {
  const int lane = threadIdx.x & 63, wid = threadIdx.x >> 6;
  const int la = lane & 31, hi = lane >> 5;
  const int wm = wid & 1, wn = wid >> 1;
  const int m0 = blockIdx.x * 64 + wm * 32;
  const int n0 = blockIdx.y * 64 + wn * 32;
  const f16* wp = W + (size_t)(n0 + la) * kD + hi * 8;
  const f16* xp = X + (size_t)(m0 + la) * kD + hi * 8;
  f16x8 wr[16], xr[16];
#pragma unroll
  for (int t = 0; t < 16; ++t) {
    wr[t] = *(const f16x8*)(wp + t * 16);
    xr[t] = *(const f16x8*)(xp + t * 16);
  }
  f32x16 acc = {};
#pragma unroll
  for (int t = 0; t < 16; ++t) acc = MFMA32_F16(wr[t], xr[t], acc, 0, 0, 0);
#pragma unroll
  for (int i = 0; i < 16; ++i)
    acc[i] += bias[n0 + (i & 3) + 8 * (i >> 2) + 4 * hi];
  if (C16) store16(acc, C16 + (size_t)(m0 + la) * kD + n0, hi);
  if (C32) {
    float* row = C32 + (size_t)(m0 + la) * kD + n0;
    float4 f0 = {acc[0], acc[1], acc[2], acc[3]};
    float4 f1 = {acc[4], acc[5], acc[6], acc[7]};
    float4 f2 = {acc[8], acc[9], acc[10], acc[11]};
    float4 f3 = {acc[12], acc[13], acc[14], acc[15]};
    *(float4*)(row + 4 * hi) = f0;
    *(float4*)(row + 8 + 4 * hi) = f1;
    *(float4*)(row + 16 + 4 * hi) = f2;
    *(float4*)(row + 24 + 4 * hi) = f3;
  }
}

// ---------- all-layer K/V projection, full-prefetch 32x32 MFMA ------------
__global__ __launch_bounds__(256) void kvall3_k(
    const f16* __restrict__ e16, const f16* __restrict__ win16,
    const float* __restrict__ inb,
    f16* __restrict__ k16all, f16* __restrict__ vt16all,
    f16* __restrict__ v16all) {
  const int lane = threadIdx.x & 63, wid = threadIdx.x >> 6;
  const int la = lane & 31, hi = lane >> 5;
  const int wm = wid & 1, wn = wid >> 1;
  const int bid = blockIdx.x;
  const int l = bid >> 10;
  const int tt = bid & 1023;
  const int bx = tt & 127, by = tt >> 7;  // by 0-3: K cols, 4-7: V cols
  const int m0 = bx * 64 + wm * 32;
  const int nb = by * 64 + wn * 32;  // 0..511 within [wk;wv]
  const f16* W = win16 + (size_t)l * 3 * kD * kD + (size_t)kD * kD;
  const float* bias = inb + (size_t)l * 3 * kD + kD;
  const f16* wp = W + (size_t)(nb + la) * kD + hi * 8;
  const f16* xp = e16 + (size_t)(m0 + la) * kD + hi * 8;

  f16x8 wr[16], xr[16];
#pragma unroll
  for (int t = 0; t < 16; ++t) {
    wr[t] = *(const f16x8*)(wp + t * 16);
    xr[t] = *(const f16x8*)(xp + t * 16);
  }

  if (by < 4) {
    f32x16 acc = {};
#pragma unroll
    for (int t = 0; t < 16; ++t) acc = MFMA32_F16(wr[t], xr[t], acc, 0, 0, 0);
#pragma unroll
    for (int i = 0; i < 16; ++i)
      acc[i] += bias[nb + (i & 3) + 8 * (i >> 2) + 4 * hi];
    store16(acc, k16all + (size_t)l * kS * kD + (size_t)(m0 + la) * kD + nb,
            hi);
  } else {
    f32x16 arm = {}, atr = {};
#pragma unroll
    for (int t = 0; t < 16; ++t) {
      arm = MFMA32_F16(wr[t], xr[t], arm, 0, 0, 0);
      atr = MFMA32_F16(xr[t], wr[t], atr, 0, 0, 0);
    }
    const int dv0 = nb - 256;
#pragma unroll
    for (int i = 0; i < 16; ++i)
      arm[i] += bias[nb + (i & 3) + 8 * (i >> 2) + 4 * hi];
    store16(arm, v16all + (size_t)l * kS * kD + (size_t)(m0 + la) * kD + dv0,
            hi);
    const float bv = bias[nb + la];
#pragma unroll
    for (int i = 0; i < 16; ++i) atr[i] += bv;
    store16(atr, vt16all + (size_t)l * kS * kD + (size_t)(dv0 + la) * kS + m0,
            hi);
  }
}

// ---------- dense attention: round-11-verified attn_dense7 (45.6 us) ------
__global__ __launch_bounds__(256, 2) void attn_dense7_k(
    const f16* __restrict__ Q, const f16* __restrict__ Km,
    const f16* __restrict__ Vt,
    f16* __restrict__ numOut, float* __restrict__ denOut) {
  __shared__ __align__(16) f16 Kl[2][64 * 128];  // [key][d], XOR-swizzled
  __shared__ __align__(16) f16 Vl[2][128 * 64];  // [d][key], XOR-swizzled
  const int tid = threadIdx.x;
  const int lane = tid & 63, wid = tid >> 6;
  const int la = lane & 31, hi = lane >> 5;
  const int id = blockIdx.x;
  const int grp = id & 15;
  const int h = grp & 1;
  const int z = grp >> 1;
  const int bx = id >> 4;
  const int q0w = bx * 128 + wid * 32;
  const int sb0 = z * (kS / kNS);
  const int nt = (kS / kNS) / 64;  // 16

  f16x8 qb[8];
#pragma unroll
  for (int kk = 0; kk < 8; ++kk)
    qb[kk] = *(const f16x8*)(Q + (size_t)(q0w + la) * kD + h * kDH + kk * 16 +
                             hi * 8);

  int kSrc[4], kDst[4], vSrc[4], vDst[4];
#pragma unroll
  for (int p = 0; p < 4; ++p) {
    int m = wid * 16 + p * 4 + (lane >> 4);
    int s = lane & 15;
    kSrc[p] = (sb0 + m) * kD + h * kDH + 8 * (s ^ (m & 7));
    kDst[p] = m * 128 + 8 * s;
    int cv = p * 256 + tid;
    int d = cv >> 3, sv = cv & 7;
    vSrc[p] = (h * kDH + d) * kS + sb0 + 8 * (sv ^ (d & 7));
    vDst[p] = d * 64 + 8 * sv;
  }

  f32x16 o0 = {}, o1 = {}, o2 = {}, o3 = {};
  float den = 0.0f;
  f16x8 kst[4], vst[4];

#pragma unroll
  for (int p = 0; p < 4; ++p) {
    kst[p] = *(const f16x8*)(Km + kSrc[p]);
    vst[p] = *(const f16x8*)(Vt + vSrc[p]);
  }
#pragma unroll
  for (int p = 0; p < 4; ++p) {
    *(f16x8*)&Kl[0][kDst[p]] = kst[p];
    *(f16x8*)&Vl[0][vDst[p]] = vst[p];
  }
  __syncthreads();

  for (int t = 0; t < nt; ++t) {
    const int cur = t & 1;
    if (t + 1 < nt) {
#pragma unroll
      for (int p = 0; p < 4; ++p) {
        kst[p] = *(const f16x8*)(Km + kSrc[p] + (t + 1) * 64 * kD);
        vst[p] = *(const f16x8*)(Vt + vSrc[p] + (t + 1) * 64);
      }
    }

    f32x16 st0 = {}, st1 = {};
    __builtin_amdgcn_s_setprio(1);
#pragma unroll
    for (int kk = 0; kk < 8; ++kk) {
      int sl = 8 * ((kk * 2 + hi) ^ (la & 7));
      f16x8 k0 = *(const f16x8*)&Kl[cur][la * 128 + sl];
      f16x8 k1 = *(const f16x8*)&Kl[cur][(32 + la) * 128 + sl];
      st0 = MFMA32_F16(k0, qb[kk], st0, 0, 0, 0);
      st1 = MFMA32_F16(k1, qb[kk], st1, 0, 0, 0);
    }
    __builtin_amdgcn_s_setprio(0);

    f32x16 pe0, pe1;
#pragma unroll
    for (int i = 0; i < 16; ++i) {
      pe0[i] = __expf(st0[i] * kScale);
      pe1[i] = __expf(st1[i] * kScale);
    }
#pragma unroll
    for (int i = 0; i < 16; ++i) den += pe0[i] + pe1[i];

    f16x8 pf[4];
    pf[0] = build_pfrag(pe0[0], pe0[1], pe0[2], pe0[3], pe0[4], pe0[5], pe0[6], pe0[7]);
    pf[1] = build_pfrag(pe0[8], pe0[9], pe0[10], pe0[11], pe0[12], pe0[13], pe0[14], pe0[15]);
    pf[2] = build_pfrag(pe1[0], pe1[1], pe1[2], pe1[3], pe1[4], pe1[5], pe1[6], pe1[7]);
    pf[3] = build_pfrag(pe1[8], pe1[9], pe1[10], pe1[11], pe1[12], pe1[13], pe1[14], pe1[15]);

    __builtin_amdgcn_s_setprio(1);
#pragma unroll
    for (int dt = 0; dt < 4; ++dt) {
      int d = dt * 32 + la;
      f32x16* op = (dt == 0) ? &o0 : (dt == 1) ? &o1 : (dt == 2) ? &o2 : &o3;
#pragma unroll
      for (int ks = 0; ks < 4; ++ks) {
        f16x8 vf = *(const f16x8*)&Vl[cur][d * 64 + 8 * ((ks * 2 + hi) ^ (d & 7))];
        *op = MFMA32_F16(vf, pf[ks], *op, 0, 0, 0);
      }
    }
    __builtin_amdgcn_s_setprio(0);

    if (t + 1 < nt) {
      const int nxt = cur ^ 1;
#pragma unroll
      for (int p = 0; p < 4; ++p) {
        *(f16x8*)&Kl[nxt][kDst[p]] = kst[p];
        *(f16x8*)&Vl[nxt][vDst[p]] = vst[p];
      }
      __syncthreads();
    }
  }

  const size_t nbase = ((size_t)z * kH + h) * kL + q0w;
  const size_t rowb = (nbase + la) * kDH;
#pragma unroll
  for (int dt = 0; dt < 4; ++dt) {
    const f32x16* op = (dt == 0) ? &o0 : (dt == 1) ? &o1 : (dt == 2) ? &o2 : &o3;
    store16(*op, numOut + rowb + dt * 32, hi);
  }
  float dq = den + __shfl_xor(den, 32);
  if (lane < 32)
    denOut[((size_t)z * kH + h) * kL + q0w + lane] = dq;
}

// ---------- fused correction + combine (round-11-verified serial form) ----
__global__ __launch_bounds__(256) void corrcomb_k(
    const unsigned int* __restrict__ loopw, const unsigned char* __restrict__ maskb,
    const int* __restrict__ flags,
    const f16* __restrict__ Q, const f16* __restrict__ Km,
    const f16* __restrict__ V,
    const f16* __restrict__ numb, const float* __restrict__ denb,
    f16* __restrict__ out16) {
  __shared__ float cvL[4][128];
  __shared__ float csL[4];
  const int lane = threadIdx.x & 63;
  const int wid = threadIdx.x >> 6;
  const int w = blockIdx.x * 4 + wid;
  const int f = w >> 1, h = w & 1;
  const int lstride = flags[0];
  const int mstride = flags[1];

  int idx = -1, valid = 0;
  if (lane < 32) {
    idx = (int)loopw[(size_t)(f * 32 + lane) * lstride];
    valid = maskb[(size_t)f * mstride] ? 1 : 0;
  }
#pragma unroll
  for (int j = 0; j < 32; ++j) {
    int oidx = __shfl(idx, j);
    if (lane < 32 && j < lane && oidx == idx) valid = 0;
  }

  const size_t qb = (size_t)f * kD + h * kDH + 2 * lane;
  const float qa = (float)Q[qb];
  const float qbv = (float)Q[qb + 1];
  float s0 = 0.0f, cv0 = 0.0f, cv1 = 0.0f;
  for (int e = 0; e < 32; ++e) {
    int ei = __shfl(idx, e);
    int ev = __shfl(valid, e);
    if (!ev) continue;
    size_t kb = (size_t)ei * kD + h * kDH + 2 * lane;
    float part = qa * (float)Km[kb] + qbv * (float)Km[kb + 1];
#pragma unroll
    for (int m = 1; m < 64; m <<= 1) part += __shfl_xor(part, m);
    float pe = __expf(part * kScale);
    s0 += pe;
    cv0 += pe * (float)V[kb];
    cv1 += pe * (float)V[kb + 1];
  }
  cvL[wid][2 * lane] = cv0;
  cvL[wid][2 * lane + 1] = cv1;
  if (lane == 0) csL[wid] = s0;
  __syncthreads();

#pragma unroll
  for (int e = 0; e < 2; ++e) {
    int idx2 = e * 256 + threadIdx.x;
    int floc = idx2 >> 8;
    int c = idx2 & 255;
    int h2 = c >> 7;
    int d = c & 127;
    int widx = floc * 2 + h2;
    int fabs_ = blockIdx.x * 2 + floc;
    float n = -cvL[widx][d];
    float dn = -csL[widx];
#pragma unroll
    for (int z = 0; z < kNS; ++z) {
      n += (float)numb[((size_t)(z * kH + h2) * kL + fabs_) * kDH + d];
      dn += denb[((size_t)z * kH + h2) * kL + fabs_];
    }
    out16[(size_t)fabs_ * kD + h2 * kDH + d] = (f16)(n / dn);
  }
}

extern "C" void kernel_launch(void* const* d_in, const int* in_sizes, int n_in,
                              void* d_out, int out_size, void* d_ws, size_t ws_size,
                              hipStream_t stream) {
  const unsigned int* loopw = (const unsigned int*)d_in[0];
  const unsigned char* fmask = (const unsigned char*)d_in[1];
  const float* edge = (const float*)d_in[2];
  const float* face = (const float*)d_in[3];
  const float* inw = (const float*)d_in[4];
  const float* inb = (const float*)d_in[5];
  const float* outw = (const float*)d_in[6];
  const float* outb = (const float*)d_in[7];
  float* out = (float*)d_out;

  char* p = (char*)d_ws;
  auto alloc = [&](size_t bytes) {
    char* q = p;
    p += (bytes + 255) & ~(size_t)255;
    return q;
  };
  int* flags = (int*)alloc(256);
  f16* e16 = (f16*)alloc((size_t)kS * kD * 2);
  f16* win16 = (f16*)alloc((size_t)kNL * 3 * kD * kD * 2);
  f16* wout16 = (f16*)alloc((size_t)kNL * kD * kD * 2);
  f16* xa = (f16*)alloc((size_t)kL * kD * 2);
  f16* q16 = (f16*)alloc((size_t)kL * kD * 2);
  f16* ao16 = (f16*)alloc((size_t)kL * kD * 2);
  f16* wqo = (f16*)alloc((size_t)3 * kD * kD * 2);
  float* bprime = (float*)alloc((size_t)3 * kD * 4);
  f16* k16all = (f16*)alloc((size_t)kNL * kS * kD * 2);
  f16* vt16all = (f16*)alloc((size_t)kNL * kS * kD * 2);
  f16* v16all = (f16*)alloc((size_t)kNL * kS * kD * 2);
  f16* numb = (f16*)alloc((size_t)kNS * kH * kL * kDH * 2);
  float* denb = (float*)alloc((size_t)kNS * kH * kL * 4);

  detect_k<<<1, 256, 0, stream>>>(loopw, fmask, flags);
  cvt_all_k<<<1024, 256, 0, stream>>>(edge, face, inw, outw, e16, xa, win16,
                                      wout16);
  compose_k<<<dim3(256, 3), 256, 0, stream>>>(inw, inb, outw, outb, wqo,
                                              bprime);
  kvall3_k<<<4096, 256, 0, stream>>>(e16, win16, inb, k16all, vt16all, v16all);

  for (int l = 0; l < kNL; ++l) {
    const f16* kl = k16all + (size_t)l * kS * kD;
    const f16* vtl = vt16all + (size_t)l * kS * kD;
    const f16* vl = v16all + (size_t)l * kS * kD;
    if (l == 0) {
      gemm32_k<<<dim3(64, 4), 256, 0, stream>>>(xa, win16, inb, q16, nullptr);
    } else {
      gemm32_k<<<dim3(64, 4), 256, 0, stream>>>(
          ao16, wqo + (size_t)(l - 1) * kD * kD, bprime + (l - 1) * kD, q16,
          nullptr);
    }
    attn_dense7_k<<<512, 256, 0, stream>>>(q16, kl, vtl, numb, denb);
    corrcomb_k<<<kL / 2, 256, 0, stream>>>(loopw, fmask, flags, q16, kl, vl,
                                           numb, denb, ao16);
  }
  // final out-projection (only layer 3's survives composition), f32 output
  gemm32_k<<<dim3(64, 4), 256, 0, stream>>>(
      ao16, wout16 + (size_t)3 * kD * kD, outb + 3 * kD, nullptr, out);
}

// Round 18
// 375.184 us; speedup vs baseline: 1.0981x; 1.0923x over previous
//
#include <hip/hip_runtime.h>
#include <math.h>

typedef _Float16 f16;
typedef _Float16 f16x4 __attribute__((ext_vector_type(4)));
typedef _Float16 f16x8 __attribute__((ext_vector_type(8)));
typedef float f32x4 __attribute__((ext_vector_type(4)));
typedef float f32x16 __attribute__((ext_vector_type(16)));

#define MFMA32_F16 __builtin_amdgcn_mfma_f32_32x32x16_f16

namespace {
constexpr int kL = 4096;   // faces (queries)
constexpr int kS = 8192;   // edges (keys/values)
constexpr int kD = 256;    // embed dim
constexpr int kH = 2;      // heads
constexpr int kDH = 128;   // head dim
constexpr int kNL = 4;     // layers
constexpr int kNS = 8;     // S-dim splits in dense attention
constexpr float kScale = 0.08838834764831845f;  // 1/sqrt(128)
}

// ---------- fused f32->f16 conversion of all inputs (one dispatch) ----------
__global__ __launch_bounds__(256) void cvt_all_k(
    const float* __restrict__ edge, const float* __restrict__ face,
    const float* __restrict__ inw, const float* __restrict__ outw,
    f16* __restrict__ e16, f16* __restrict__ xa,
    f16* __restrict__ win16, f16* __restrict__ wout16) {
  for (int i = blockIdx.x * 256 + threadIdx.x; i < 1048576; i += 1024 * 256) {
    const float* src;
    f16* dst;
    int off;
    if (i < 524288) { src = edge; dst = e16; off = i; }
    else if (i < 786432) { src = face; dst = xa; off = i - 524288; }
    else if (i < 983040) { src = inw; dst = win16; off = i - 786432; }
    else { src = outw; dst = wout16; off = i - 983040; }
    float4 v = *(const float4*)(src + 4 * (size_t)off);
    f16x4 h;
    h[0] = (f16)v.x; h[1] = (f16)v.y; h[2] = (f16)v.z; h[3] = (f16)v.w;
    *(f16x4*)(dst + 4 * (size_t)off) = h;
  }
}

// Detect on-device element widths of loop (int32/int64) and mask (1/4/8 B).
__global__ __launch_bounds__(256) void detect_k(const unsigned int* __restrict__ loopw,
                                                const unsigned char* __restrict__ maskb,
                                                int* __restrict__ flags) {
  __shared__ unsigned int s[3];
  if (threadIdx.x < 3) s[threadIdx.x] = 0;
  __syncthreads();
  unsigned int orodd = 0;
  for (int i = 1 + 2 * threadIdx.x; i < 2048; i += 512) orodd |= loopw[i];
  unsigned int nz1 = 0, nz4 = 0;
  for (int i = threadIdx.x; i < 512; i += 256) {
    unsigned char b = maskb[i];
    if ((i & 3) != 0) nz1 |= b;
    if ((i & 7) == 4) nz4 |= b;
  }
  atomicOr(&s[0], orodd);
  atomicOr(&s[1], nz1);
  atomicOr(&s[2], nz4);
  __syncthreads();
  if (threadIdx.x == 0) {
    flags[0] = (s[0] == 0) ? 2 : 1;
    flags[1] = s[1] ? 1 : (s[2] ? 4 : 8);
  }
}

// ---------- weight composition: wqo_l = wq_l . wo_{l-1}, b' = wq_l.bo + bq --
__global__ __launch_bounds__(256) void compose_k(
    const float* __restrict__ inw, const float* __restrict__ inb,
    const float* __restrict__ outw, const float* __restrict__ outb,
    f16* __restrict__ wqo, float* __restrict__ bprime) {
  const int lc = blockIdx.y;  // 0..2 -> layer l = lc+1
  const int i = blockIdx.x;   // output row
  const int j = threadIdx.x;  // output col
  const int l = lc + 1;
  const float* wq = inw + (size_t)l * 3 * kD * kD;
  const float* wo = outw + (size_t)lc * kD * kD;
  float acc = 0.0f;
  for (int k = 0; k < kD; ++k)
    acc += wq[i * kD + k] * wo[k * kD + j];
  wqo[((size_t)lc * kD + i) * kD + j] = (f16)acc;

  float t = wq[i * kD + j] * outb[lc * kD + j];
  __shared__ float red[4];
#pragma unroll
  for (int m = 1; m < 64; m <<= 1) t += __shfl_xor(t, m);
  if ((threadIdx.x & 63) == 0) red[threadIdx.x >> 6] = t;
  __syncthreads();
  if (threadIdx.x == 0)
    bprime[lc * kD + i] = red[0] + red[1] + red[2] + red[3] + inb[l * 3 * kD + i];
}

// ---------- helpers: pkh / pswap / verified 16-f32 -> 2x f16x8 epilogue ----
__device__ __forceinline__ unsigned pkh(float a, float b) {
  auto h2 = __builtin_amdgcn_cvt_pkrtz(a, b);
  return __builtin_bit_cast(unsigned, h2);
}
__device__ __forceinline__ void pswap(unsigned a, unsigned b, unsigned& x,
                                      unsigned& y) {
  typedef int i32x2 __attribute__((ext_vector_type(2)));
  i32x2 rr = __builtin_amdgcn_permlane32_swap((int)a, (int)b, false, false);
  x = (unsigned)rr[0];
  y = (unsigned)rr[1];
}
__device__ __forceinline__ f16x8 build_pfrag(float p0, float p1, float p2,
                                             float p3, float p4, float p5,
                                             float p6, float p7) {
  unsigned a0 = pkh(p0, p1), b0 = pkh(p4, p5);
  unsigned a1 = pkh(p2, p3), b1 = pkh(p6, p7);
  unsigned w0, w1, w2, w3;
  pswap(a0, b0, w0, w2);
  pswap(a1, b1, w1, w3);
  union { unsigned u[4]; f16x8 v; } r;
  r.u[0] = w0; r.u[1] = w1; r.u[2] = w2; r.u[3] = w3;
  return r.v;
}
// Store a 32x32 C-fragment row (f32x16, col=lane&31, row=(i&3)+8*(i>>2)+4*hi)
// as two f16x8 stores at base+hi*8 and base+16+hi*8 (round-10/11-verified).
__device__ __forceinline__ void store16(const f32x16& a, f16* base, int hi) {
  unsigned u01 = pkh(a[0], a[1]), u23 = pkh(a[2], a[3]);
  unsigned u89 = pkh(a[4], a[5]), uab = pkh(a[6], a[7]);
  unsigned w0, w1, w2, w3;
  pswap(u01, u89, w0, w2);
  pswap(u23, uab, w1, w3);
  union { unsigned u[4]; f16x8 v; } r1;
  r1.u[0] = w0; r1.u[1] = w1; r1.u[2] = w2; r1.u[3] = w3;
  *(f16x8*)(base + hi * 8) = r1.v;
  unsigned v01 = pkh(a[8], a[9]), v23 = pkh(a[10], a[11]);
  unsigned v89 = pkh(a[12], a[13]), vab = pkh(a[14], a[15]);
  unsigned x0, x1, x2, x3;
  pswap(v01, v89, x0, x2);
  pswap(v23, vab, x1, x3);
  union { unsigned u[4]; f16x8 v; } r2;
  r2.u[0] = x0; r2.u[1] = x1; r2.u[2] = x2; r2.u[3] = x3;
  *(f16x8*)(base + 16 + hi * 8) = r2.v;
}

// ---------- generic 32x32-MFMA GEMM: C = X @ W^T + bias (M rows, N=K=256) --
__global__ __launch_bounds__(256) void gemm32_k(
    const f16* __restrict__ X, const f16* __restrict__ W,
    const float* __restrict__ bias, f16* __restrict__ C16,
    float* __restrict__ C32) {
  const int lane = threadIdx.x & 63, wid = threadIdx.x >> 6;
  const int la = lane & 31, hi = lane >> 5;
  const int wm = wid & 1, wn = wid >> 1;
  const int m0 = blockIdx.x * 64 + wm * 32;
  const int n0 = blockIdx.y * 64 + wn * 32;
  const f16* wp = W + (size_t)(n0 + la) * kD + hi * 8;
  const f16* xp = X + (size_t)(m0 + la) * kD + hi * 8;
  f16x8 wr[16], xr[16];
#pragma unroll
  for (int t = 0; t < 16; ++t) {
    wr[t] = *(const f16x8*)(wp + t * 16);
    xr[t] = *(const f16x8*)(xp + t * 16);
  }
  f32x16 acc = {};
#pragma unroll
  for (int t = 0; t < 16; ++t) acc = MFMA32_F16(wr[t], xr[t], acc, 0, 0, 0);
#pragma unroll
  for (int i = 0; i < 16; ++i)
    acc[i] += bias[n0 + (i & 3) + 8 * (i >> 2) + 4 * hi];
  if (C16) store16(acc, C16 + (size_t)(m0 + la) * kD + n0, hi);
  if (C32) {
    float* row = C32 + (size_t)(m0 + la) * kD + n0;
    float4 f0 = {acc[0], acc[1], acc[2], acc[3]};
    float4 f1 = {acc[4], acc[5], acc[6], acc[7]};
    float4 f2 = {acc[8], acc[9], acc[10], acc[11]};
    float4 f3 = {acc[12], acc[13], acc[14], acc[15]};
    *(float4*)(row + 4 * hi) = f0;
    *(float4*)(row + 8 + 4 * hi) = f1;
    *(float4*)(row + 16 + 4 * hi) = f2;
    *(float4*)(row + 24 + 4 * hi) = f3;
  }
}

// ---------- all-layer K/V projection: LDS-staged operands ------------------
// Round-17 counters (MfmaUtil 6.8%, VALU 4.8%, traffic minimal) showed the
// direct-global fragment loads are 32-line-per-instruction gathers. Stage
// X-tile and W-tile [64][256] in LDS via coalesced loads (pre-XOR-swizzled
// source, linear dest -- the attn_dense7-verified idiom), read fragments
// with the verified (2t+hi)^(row&7) swizzle. Epilogues verbatim kvall3.
__global__ __launch_bounds__(256) void kvall4_k(
    const f16* __restrict__ e16, const f16* __restrict__ win16,
    const float* __restrict__ inb,
    f16* __restrict__ k16all, f16* __restrict__ vt16all,
    f16* __restrict__ v16all) {
  __shared__ __align__(16) f16 Xl[64 * 256];
  __shared__ __align__(16) f16 Wl[64 * 256];
  const int tid = threadIdx.x;
  const int lane = tid & 63, wid = tid >> 6;
  const int la = lane & 31, hi = lane >> 5;
  const int wm = wid & 1, wn = wid >> 1;
  const int bid = blockIdx.x;
  const int l = bid >> 10;
  const int tt = bid & 1023;
  const int bx = tt & 127, by = tt >> 7;  // by 0-3: K cols, 4-7: V cols
  const int e0 = bx * 64, n0 = by * 64;
  const f16* W = win16 + (size_t)l * 3 * kD * kD + (size_t)kD * kD;
  const float* bias = inb + (size_t)l * 3 * kD + kD;

  // stage both tiles: coalesced global loads, linear LDS dest
  f16x8 xst[8], wst[8];
#pragma unroll
  for (int p = 0; p < 8; ++p) {
    int id = p * 256 + tid;
    int row = id >> 5, s = id & 31;
    xst[p] = *(const f16x8*)(e16 + (size_t)(e0 + row) * kD + 8 * (s ^ (row & 7)));
    wst[p] = *(const f16x8*)(W + (size_t)(n0 + row) * kD + 8 * (s ^ (row & 7)));
  }
#pragma unroll
  for (int p = 0; p < 8; ++p) {
    int id = p * 256 + tid;
    *(f16x8*)&Xl[8 * id] = xst[p];
    *(f16x8*)&Wl[8 * id] = wst[p];
  }
  __syncthreads();

  // fragment reads from LDS (swizzled, conflict-light)
  const int xrow = wm * 32 + la, wrow = wn * 32 + la;
  f16x8 wr[16], xr[16];
#pragma unroll
  for (int t = 0; t < 16; ++t) {
    xr[t] = *(const f16x8*)&Xl[xrow * 256 + 8 * ((2 * t + hi) ^ (xrow & 7))];
    wr[t] = *(const f16x8*)&Wl[wrow * 256 + 8 * ((2 * t + hi) ^ (wrow & 7))];
  }

  const int m0 = e0 + wm * 32;
  const int nb = n0 + wn * 32;
  if (by < 4) {
    f32x16 acc = {};
#pragma unroll
    for (int t = 0; t < 16; ++t) acc = MFMA32_F16(wr[t], xr[t], acc, 0, 0, 0);
#pragma unroll
    for (int i = 0; i < 16; ++i)
      acc[i] += bias[nb + (i & 3) + 8 * (i >> 2) + 4 * hi];
    store16(acc, k16all + (size_t)l * kS * kD + (size_t)(m0 + la) * kD + nb,
            hi);
  } else {
    f32x16 arm = {}, atr = {};
#pragma unroll
    for (int t = 0; t < 16; ++t) {
      arm = MFMA32_F16(wr[t], xr[t], arm, 0, 0, 0);
      atr = MFMA32_F16(xr[t], wr[t], atr, 0, 0, 0);
    }
    const int dv0 = nb - 256;
#pragma unroll
    for (int i = 0; i < 16; ++i)
      arm[i] += bias[nb + (i & 3) + 8 * (i >> 2) + 4 * hi];
    store16(arm, v16all + (size_t)l * kS * kD + (size_t)(m0 + la) * kD + dv0,
            hi);
    const float bv = bias[nb + la];
#pragma unroll
    for (int i = 0; i < 16; ++i) atr[i] += bv;
    store16(atr, vt16all + (size_t)l * kS * kD + (size_t)(dv0 + la) * kS + m0,
            hi);
  }
}

// ---------- dense attention: round-11-verified attn_dense7 (45.6 us) ------
__global__ __launch_bounds__(256, 2) void attn_dense7_k(
    const f16* __restrict__ Q, const f16* __restrict__ Km,
    const f16* __restrict__ Vt,
    f16* __restrict__ numOut, float* __restrict__ denOut) {
  __shared__ __align__(16) f16 Kl[2][64 * 128];  // [key][d], XOR-swizzled
  __shared__ __align__(16) f16 Vl[2][128 * 64];  // [d][key], XOR-swizzled
  const int tid = threadIdx.x;
  const int lane = tid & 63, wid = tid >> 6;
  const int la = lane & 31, hi = lane >> 5;
  const int id = blockIdx.x;
  const int grp = id & 15;
  const int h = grp & 1;
  const int z = grp >> 1;
  const int bx = id >> 4;
  const int q0w = bx * 128 + wid * 32;
  const int sb0 = z * (kS / kNS);
  const int nt = (kS / kNS) / 64;  // 16

  f16x8 qb[8];
#pragma unroll
  for (int kk = 0; kk < 8; ++kk)
    qb[kk] = *(const f16x8*)(Q + (size_t)(q0w + la) * kD + h * kDH + kk * 16 +
                             hi * 8);

  int kSrc[4], kDst[4], vSrc[4], vDst[4];
#pragma unroll
  for (int p = 0; p < 4; ++p) {
    int m = wid * 16 + p * 4 + (lane >> 4);
    int s = lane & 15;
    kSrc[p] = (sb0 + m) * kD + h * kDH + 8 * (s ^ (m & 7));
    kDst[p] = m * 128 + 8 * s;
    int cv = p * 256 + tid;
    int d = cv >> 3, sv = cv & 7;
    vSrc[p] = (h * kDH + d) * kS + sb0 + 8 * (sv ^ (d & 7));
    vDst[p] = d * 64 + 8 * sv;
  }

  f32x16 o0 = {}, o1 = {}, o2 = {}, o3 = {};
  float den = 0.0f;
  f16x8 kst[4], vst[4];

#pragma unroll
  for (int p = 0; p < 4; ++p) {
    kst[p] = *(const f16x8*)(Km + kSrc[p]);
    vst[p] = *(const f16x8*)(Vt + vSrc[p]);
  }
#pragma unroll
  for (int p = 0; p < 4; ++p) {
    *(f16x8*)&Kl[0][kDst[p]] = kst[p];
    *(f16x8*)&Vl[0][vDst[p]] = vst[p];
  }
  __syncthreads();

  for (int t = 0; t < nt; ++t) {
    const int cur = t & 1;
    if (t + 1 < nt) {
#pragma unroll
      for (int p = 0; p < 4; ++p) {
        kst[p] = *(const f16x8*)(Km + kSrc[p] + (t + 1) * 64 * kD);
        vst[p] = *(const f16x8*)(Vt + vSrc[p] + (t + 1) * 64);
      }
    }

    f32x16 st0 = {}, st1 = {};
    __builtin_amdgcn_s_setprio(1);
#pragma unroll
    for (int kk = 0; kk < 8; ++kk) {
      int sl = 8 * ((kk * 2 + hi) ^ (la & 7));
      f16x8 k0 = *(const f16x8*)&Kl[cur][la * 128 + sl];
      f16x8 k1 = *(const f16x8*)&Kl[cur][(32 + la) * 128 + sl];
      st0 = MFMA32_F16(k0, qb[kk], st0, 0, 0, 0);
      st1 = MFMA32_F16(k1, qb[kk], st1, 0, 0, 0);
    }
    __builtin_amdgcn_s_setprio(0);

    f32x16 pe0, pe1;
#pragma unroll
    for (int i = 0; i < 16; ++i) {
      pe0[i] = __expf(st0[i] * kScale);
      pe1[i] = __expf(st1[i] * kScale);
    }
#pragma unroll
    for (int i = 0; i < 16; ++i) den += pe0[i] + pe1[i];

    f16x8 pf[4];
    pf[0] = build_pfrag(pe0[0], pe0[1], pe0[2], pe0[3], pe0[4], pe0[5], pe0[6], pe0[7]);
    pf[1] = build_pfrag(pe0[8], pe0[9], pe0[10], pe0[11], pe0[12], pe0[13], pe0[14], pe0[15]);
    pf[2] = build_pfrag(pe1[0], pe1[1], pe1[2], pe1[3], pe1[4], pe1[5], pe1[6], pe1[7]);
    pf[3] = build_pfrag(pe1[8], pe1[9], pe1[10], pe1[11], pe1[12], pe1[13], pe1[14], pe1[15]);

    __builtin_amdgcn_s_setprio(1);
#pragma unroll
    for (int dt = 0; dt < 4; ++dt) {
      int d = dt * 32 + la;
      f32x16* op = (dt == 0) ? &o0 : (dt == 1) ? &o1 : (dt == 2) ? &o2 : &o3;
#pragma unroll
      for (int ks = 0; ks < 4; ++ks) {
        f16x8 vf = *(const f16x8*)&Vl[cur][d * 64 + 8 * ((ks * 2 + hi) ^ (d & 7))];
        *op = MFMA32_F16(vf, pf[ks], *op, 0, 0, 0);
      }
    }
    __builtin_amdgcn_s_setprio(0);

    if (t + 1 < nt) {
      const int nxt = cur ^ 1;
#pragma unroll
      for (int p = 0; p < 4; ++p) {
        *(f16x8*)&Kl[nxt][kDst[p]] = kst[p];
        *(f16x8*)&Vl[nxt][vDst[p]] = vst[p];
      }
      __syncthreads();
    }
  }

  const size_t nbase = ((size_t)z * kH + h) * kL + q0w;
  const size_t rowb = (nbase + la) * kDH;
#pragma unroll
  for (int dt = 0; dt < 4; ++dt) {
    const f32x16* op = (dt == 0) ? &o0 : (dt == 1) ? &o1 : (dt == 2) ? &o2 : &o3;
    store16(*op, numOut + rowb + dt * 32, hi);
  }
  float dq = den + __shfl_xor(den, 32);
  if (lane < 32)
    denOut[((size_t)z * kH + h) * kL + q0w + lane] = dq;
}

// ---------- fused correction + combine (round-11-verified serial form) ----
__global__ __launch_bounds__(256) void corrcomb_k(
    const unsigned int* __restrict__ loopw, const unsigned char* __restrict__ maskb,
    const int* __restrict__ flags,
    const f16* __restrict__ Q, const f16* __restrict__ Km,
    const f16* __restrict__ V,
    const f16* __restrict__ numb, const float* __restrict__ denb,
    f16* __restrict__ out16) {
  __shared__ float cvL[4][128];
  __shared__ float csL[4];
  const int lane = threadIdx.x & 63;
  const int wid = threadIdx.x >> 6;
  const int w = blockIdx.x * 4 + wid;
  const int f = w >> 1, h = w & 1;
  const int lstride = flags[0];
  const int mstride = flags[1];

  int idx = -1, valid = 0;
  if (lane < 32) {
    idx = (int)loopw[(size_t)(f * 32 + lane) * lstride];
    valid = maskb[(size_t)f * mstride] ? 1 : 0;
  }
#pragma unroll
  for (int j = 0; j < 32; ++j) {
    int oidx = __shfl(idx, j);
    if (lane < 32 && j < lane && oidx == idx) valid = 0;
  }

  const size_t qb = (size_t)f * kD + h * kDH + 2 * lane;
  const float qa = (float)Q[qb];
  const float qbv = (float)Q[qb + 1];
  float s0 = 0.0f, cv0 = 0.0f, cv1 = 0.0f;
  for (int e = 0; e < 32; ++e) {
    int ei = __shfl(idx, e);
    int ev = __shfl(valid, e);
    if (!ev) continue;
    size_t kb = (size_t)ei * kD + h * kDH + 2 * lane;
    float part = qa * (float)Km[kb] + qbv * (float)Km[kb + 1];
#pragma unroll
    for (int m = 1; m < 64; m <<= 1) part += __shfl_xor(part, m);
    float pe = __expf(part * kScale);
    s0 += pe;
    cv0 += pe * (float)V[kb];
    cv1 += pe * (float)V[kb + 1];
  }
  cvL[wid][2 * lane] = cv0;
  cvL[wid][2 * lane + 1] = cv1;
  if (lane == 0) csL[wid] = s0;
  __syncthreads();

#pragma unroll
  for (int e = 0; e < 2; ++e) {
    int idx2 = e * 256 + threadIdx.x;
    int floc = idx2 >> 8;
    int c = idx2 & 255;
    int h2 = c >> 7;
    int d = c & 127;
    int widx = floc * 2 + h2;
    int fabs_ = blockIdx.x * 2 + floc;
    float n = -cvL[widx][d];
    float dn = -csL[widx];
#pragma unroll
    for (int z = 0; z < kNS; ++z) {
      n += (float)numb[((size_t)(z * kH + h2) * kL + fabs_) * kDH + d];
      dn += denb[((size_t)z * kH + h2) * kL + fabs_];
    }
    out16[(size_t)fabs_ * kD + h2 * kDH + d] = (f16)(n / dn);
  }
}

extern "C" void kernel_launch(void* const* d_in, const int* in_sizes, int n_in,
                              void* d_out, int out_size, void* d_ws, size_t ws_size,
                              hipStream_t stream) {
  const unsigned int* loopw = (const unsigned int*)d_in[0];
  const unsigned char* fmask = (const unsigned char*)d_in[1];
  const float* edge = (const float*)d_in[2];
  const float* face = (const float*)d_in[3];
  const float* inw = (const float*)d_in[4];
  const float* inb = (const float*)d_in[5];
  const float* outw = (const float*)d_in[6];
  const float* outb = (const float*)d_in[7];
  float* out = (float*)d_out;

  char* p = (char*)d_ws;
  auto alloc = [&](size_t bytes) {
    char* q = p;
    p += (bytes + 255) & ~(size_t)255;
    return q;
  };
  int* flags = (int*)alloc(256);
  f16* e16 = (f16*)alloc((size_t)kS * kD * 2);
  f16* win16 = (f16*)alloc((size_t)kNL * 3 * kD * kD * 2);
  f16* wout16 = (f16*)alloc((size_t)kNL * kD * kD * 2);
  f16* xa = (f16*)alloc((size_t)kL * kD * 2);
  f16* q16 = (f16*)alloc((size_t)kL * kD * 2);
  f16* ao16 = (f16*)alloc((size_t)kL * kD * 2);
  f16* wqo = (f16*)alloc((size_t)3 * kD * kD * 2);
  float* bprime = (float*)alloc((size_t)3 * kD * 4);
  f16* k16all = (f16*)alloc((size_t)kNL * kS * kD * 2);
  f16* vt16all = (f16*)alloc((size_t)kNL * kS * kD * 2);
  f16* v16all = (f16*)alloc((size_t)kNL * kS * kD * 2);
  f16* numb = (f16*)alloc((size_t)kNS * kH * kL * kDH * 2);
  float* denb = (float*)alloc((size_t)kNS * kH * kL * 4);

  detect_k<<<1, 256, 0, stream>>>(loopw, fmask, flags);
  cvt_all_k<<<1024, 256, 0, stream>>>(edge, face, inw, outw, e16, xa, win16,
                                      wout16);
  compose_k<<<dim3(256, 3), 256, 0, stream>>>(inw, inb, outw, outb, wqo,
                                              bprime);
  kvall4_k<<<4096, 256, 0, stream>>>(e16, win16, inb, k16all, vt16all, v16all);

  for (int l = 0; l < kNL; ++l) {
    const f16* kl = k16all + (size_t)l * kS * kD;
    const f16* vtl = vt16all + (size_t)l * kS * kD;
    const f16* vl = v16all + (size_t)l * kS * kD;
    if (l == 0) {
      gemm32_k<<<dim3(64, 4), 256, 0, stream>>>(xa, win16, inb, q16, nullptr);
    } else {
      gemm32_k<<<dim3(64, 4), 256, 0, stream>>>(
          ao16, wqo + (size_t)(l - 1) * kD * kD, bprime + (l - 1) * kD, q16,
          nullptr);
    }
    attn_dense7_k<<<512, 256, 0, stream>>>(q16, kl, vtl, numb, denb);
    corrcomb_k<<<kL / 2, 256, 0, stream>>>(loopw, fmask, flags, q16, kl, vl,
                                           numb, denb, ao16);
  }
  // final out-projection (only layer 3's survives composition), f32 output
  gemm32_k<<<dim3(64, 4), 256, 0, stream>>>(
      ao16, wout16 + (size_t)3 * kD * kD, outb + 3 * kD, nullptr, out);
}

// Round 19
// 366.026 us; speedup vs baseline: 1.1255x; 1.0250x over previous
//
#include <hip/hip_runtime.h>
#include <math.h>

typedef _Float16 f16;
typedef _Float16 f16x4 __attribute__((ext_vector_type(4)));
typedef _Float16 f16x8 __attribute__((ext_vector_type(8)));
typedef float f32x4 __attribute__((ext_vector_type(4)));
typedef float f32x16 __attribute__((ext_vector_type(16)));

#define MFMA32_F16 __builtin_amdgcn_mfma_f32_32x32x16_f16

namespace {
constexpr int kL = 4096;   // faces (queries)
constexpr int kS = 8192;   // edges (keys/values)
constexpr int kD = 256;    // embed dim
constexpr int kH = 2;      // heads
constexpr int kDH = 128;   // head dim
constexpr int kNL = 4;     // layers
constexpr int kNS = 8;     // S-dim splits in dense attention
constexpr float kScale = 0.08838834764831845f;  // 1/sqrt(128)
}

// ---------- fused f32->f16 conversion of all inputs (one dispatch) ----------
__global__ __launch_bounds__(256) void cvt_all_k(
    const float* __restrict__ edge, const float* __restrict__ face,
    const float* __restrict__ inw, const float* __restrict__ outw,
    f16* __restrict__ e16, f16* __restrict__ xa,
    f16* __restrict__ win16, f16* __restrict__ wout16) {
  for (int i = blockIdx.x * 256 + threadIdx.x; i < 1048576; i += 1024 * 256) {
    const float* src;
    f16* dst;
    int off;
    if (i < 524288) { src = edge; dst = e16; off = i; }
    else if (i < 786432) { src = face; dst = xa; off = i - 524288; }
    else if (i < 983040) { src = inw; dst = win16; off = i - 786432; }
    else { src = outw; dst = wout16; off = i - 983040; }
    float4 v = *(const float4*)(src + 4 * (size_t)off);
    f16x4 h;
    h[0] = (f16)v.x; h[1] = (f16)v.y; h[2] = (f16)v.z; h[3] = (f16)v.w;
    *(f16x4*)(dst + 4 * (size_t)off) = h;
  }
}

// Detect on-device element widths of loop (int32/int64) and mask (1/4/8 B).
__global__ __launch_bounds__(256) void detect_k(const unsigned int* __restrict__ loopw,
                                                const unsigned char* __restrict__ maskb,
                                                int* __restrict__ flags) {
  __shared__ unsigned int s[3];
  if (threadIdx.x < 3) s[threadIdx.x] = 0;
  __syncthreads();
  unsigned int orodd = 0;
  for (int i = 1 + 2 * threadIdx.x; i < 2048; i += 512) orodd |= loopw[i];
  unsigned int nz1 = 0, nz4 = 0;
  for (int i = threadIdx.x; i < 512; i += 256) {
    unsigned char b = maskb[i];
    if ((i & 3) != 0) nz1 |= b;
    if ((i & 7) == 4) nz4 |= b;
  }
  atomicOr(&s[0], orodd);
  atomicOr(&s[1], nz1);
  atomicOr(&s[2], nz4);
  __syncthreads();
  if (threadIdx.x == 0) {
    flags[0] = (s[0] == 0) ? 2 : 1;
    flags[1] = s[1] ? 1 : (s[2] ? 4 : 8);
  }
}

// ---------- weight composition: wqo_l = wq_l . wo_{l-1}, b' = wq_l.bo + bq --
__global__ __launch_bounds__(256) void compose_k(
    const float* __restrict__ inw, const float* __restrict__ inb,
    const float* __restrict__ outw, const float* __restrict__ outb,
    f16* __restrict__ wqo, float* __restrict__ bprime) {
  const int lc = blockIdx.y;  // 0..2 -> layer l = lc+1
  const int i = blockIdx.x;   // output row
  const int j = threadIdx.x;  // output col
  const int l = lc + 1;
  const float* wq = inw + (size_t)l * 3 * kD * kD;
  const float* wo = outw + (size_t)lc * kD * kD;
  float acc = 0.0f;
  for (int k = 0; k < kD; ++k)
    acc += wq[i * kD + k] * wo[k * kD + j];
  wqo[((size_t)lc * kD + i) * kD + j] = (f16)acc;

  float t = wq[i * kD + j] * outb[lc * kD + j];
  __shared__ float red[4];
#pragma unroll
  for (int m = 1; m < 64; m <<= 1) t += __shfl_xor(t, m);
  if ((threadIdx.x & 63) == 0) red[threadIdx.x >> 6] = t;
  __syncthreads();
  if (threadIdx.x == 0)
    bprime[lc * kD + i] = red[0] + red[1] + red[2] + red[3] + inb[l * 3 * kD + i];
}

// ---------- helpers: pkh / pswap / verified 16-f32 -> 2x f16x8 epilogue ----
__device__ __forceinline__ unsigned pkh(float a, float b) {
  auto h2 = __builtin_amdgcn_cvt_pkrtz(a, b);
  return __builtin_bit_cast(unsigned, h2);
}
__device__ __forceinline__ void pswap(unsigned a, unsigned b, unsigned& x,
                                      unsigned& y) {
  typedef int i32x2 __attribute__((ext_vector_type(2)));
  i32x2 rr = __builtin_amdgcn_permlane32_swap((int)a, (int)b, false, false);
  x = (unsigned)rr[0];
  y = (unsigned)rr[1];
}
__device__ __forceinline__ f16x8 build_pfrag(float p0, float p1, float p2,
                                             float p3, float p4, float p5,
                                             float p6, float p7) {
  unsigned a0 = pkh(p0, p1), b0 = pkh(p4, p5);
  unsigned a1 = pkh(p2, p3), b1 = pkh(p6, p7);
  unsigned w0, w1, w2, w3;
  pswap(a0, b0, w0, w2);
  pswap(a1, b1, w1, w3);
  union { unsigned u[4]; f16x8 v; } r;
  r.u[0] = w0; r.u[1] = w1; r.u[2] = w2; r.u[3] = w3;
  return r.v;
}
// Store a 32x32 C-fragment row (f32x16, col=lane&31, row=(i&3)+8*(i>>2)+4*hi)
// as two f16x8 stores at base+hi*8 and base+16+hi*8 (round-10/11-verified).
__device__ __forceinline__ void store16(const f32x16& a, f16* base, int hi) {
  unsigned u01 = pkh(a[0], a[1]), u23 = pkh(a[2], a[3]);
  unsigned u89 = pkh(a[4], a[5]), uab = pkh(a[6], a[7]);
  unsigned w0, w1, w2, w3;
  pswap(u01, u89, w0, w2);
  pswap(u23, uab, w1, w3);
  union { unsigned u[4]; f16x8 v; } r1;
  r1.u[0] = w0; r1.u[1] = w1; r1.u[2] = w2; r1.u[3] = w3;
  *(f16x8*)(base + hi * 8) = r1.v;
  unsigned v01 = pkh(a[8], a[9]), v23 = pkh(a[10], a[11]);
  unsigned v89 = pkh(a[12], a[13]), vab = pkh(a[14], a[15]);
  unsigned x0, x1, x2, x3;
  pswap(v01, v89, x0, x2);
  pswap(v23, vab, x1, x3);
  union { unsigned u[4]; f16x8 v; } r2;
  r2.u[0] = x0; r2.u[1] = x1; r2.u[2] = x2; r2.u[3] = x3;
  *(f16x8*)(base + 16 + hi * 8) = r2.v;
}

// ---------- 32x32-MFMA GEMM with LDS-staged operands (kvall4 pattern) ------
// C = X @ W^T + bias. Stage X-tile/W-tile [64][256] via coalesced loads
// (pre-XOR-swizzled source, linear dest); fragment reads use the verified
// (2t+hi)^(row&7) swizzle. Fixes the 32-line-per-instruction global gathers
// that kept the direct-global version latency-bound (rounds 15-17).
__global__ __launch_bounds__(256) void gemm32s_k(
    const f16* __restrict__ X, const f16* __restrict__ W,
    const float* __restrict__ bias, f16* __restrict__ C16,
    float* __restrict__ C32) {
  __shared__ __align__(16) f16 Xl[64 * 256];
  __shared__ __align__(16) f16 Wl[64 * 256];
  const int tid = threadIdx.x;
  const int lane = tid & 63, wid = tid >> 6;
  const int la = lane & 31, hi = lane >> 5;
  const int wm = wid & 1, wn = wid >> 1;
  const int m0b = blockIdx.x * 64, n0b = blockIdx.y * 64;

  f16x8 xst[8], wst[8];
#pragma unroll
  for (int p = 0; p < 8; ++p) {
    int id = p * 256 + tid;
    int row = id >> 5, s = id & 31;
    xst[p] = *(const f16x8*)(X + (size_t)(m0b + row) * kD + 8 * (s ^ (row & 7)));
    wst[p] = *(const f16x8*)(W + (size_t)(n0b + row) * kD + 8 * (s ^ (row & 7)));
  }
#pragma unroll
  for (int p = 0; p < 8; ++p) {
    int id = p * 256 + tid;
    *(f16x8*)&Xl[8 * id] = xst[p];
    *(f16x8*)&Wl[8 * id] = wst[p];
  }
  __syncthreads();

  const int xrow = wm * 32 + la, wrow = wn * 32 + la;
  f16x8 wr[16], xr[16];
#pragma unroll
  for (int t = 0; t < 16; ++t) {
    xr[t] = *(const f16x8*)&Xl[xrow * 256 + 8 * ((2 * t + hi) ^ (xrow & 7))];
    wr[t] = *(const f16x8*)&Wl[wrow * 256 + 8 * ((2 * t + hi) ^ (wrow & 7))];
  }

  const int m0 = m0b + wm * 32;
  const int n0 = n0b + wn * 32;
  f32x16 acc = {};
#pragma unroll
  for (int t = 0; t < 16; ++t) acc = MFMA32_F16(wr[t], xr[t], acc, 0, 0, 0);
#pragma unroll
  for (int i = 0; i < 16; ++i)
    acc[i] += bias[n0 + (i & 3) + 8 * (i >> 2) + 4 * hi];
  if (C16) store16(acc, C16 + (size_t)(m0 + la) * kD + n0, hi);
  if (C32) {
    float* row = C32 + (size_t)(m0 + la) * kD + n0;
    float4 f0 = {acc[0], acc[1], acc[2], acc[3]};
    float4 f1 = {acc[4], acc[5], acc[6], acc[7]};
    float4 f2 = {acc[8], acc[9], acc[10], acc[11]};
    float4 f3 = {acc[12], acc[13], acc[14], acc[15]};
    *(float4*)(row + 4 * hi) = f0;
    *(float4*)(row + 8 + 4 * hi) = f1;
    *(float4*)(row + 16 + 4 * hi) = f2;
    *(float4*)(row + 24 + 4 * hi) = f3;
  }
}

// ---------- all-layer K/V projection: LDS-staged operands (round-18) -------
__global__ __launch_bounds__(256) void kvall4_k(
    const f16* __restrict__ e16, const f16* __restrict__ win16,
    const float* __restrict__ inb,
    f16* __restrict__ k16all, f16* __restrict__ vt16all,
    f16* __restrict__ v16all) {
  __shared__ __align__(16) f16 Xl[64 * 256];
  __shared__ __align__(16) f16 Wl[64 * 256];
  const int tid = threadIdx.x;
  const int lane = tid & 63, wid = tid >> 6;
  const int la = lane & 31, hi = lane >> 5;
  const int wm = wid & 1, wn = wid >> 1;
  const int bid = blockIdx.x;
  const int l = bid >> 10;
  const int tt = bid & 1023;
  const int bx = tt & 127, by = tt >> 7;  // by 0-3: K cols, 4-7: V cols
  const int e0 = bx * 64, n0 = by * 64;
  const f16* W = win16 + (size_t)l * 3 * kD * kD + (size_t)kD * kD;
  const float* bias = inb + (size_t)l * 3 * kD + kD;

  f16x8 xst[8], wst[8];
#pragma unroll
  for (int p = 0; p < 8; ++p) {
    int id = p * 256 + tid;
    int row = id >> 5, s = id & 31;
    xst[p] = *(const f16x8*)(e16 + (size_t)(e0 + row) * kD + 8 * (s ^ (row & 7)));
    wst[p] = *(const f16x8*)(W + (size_t)(n0 + row) * kD + 8 * (s ^ (row & 7)));
  }
#pragma unroll
  for (int p = 0; p < 8; ++p) {
    int id = p * 256 + tid;
    *(f16x8*)&Xl[8 * id] = xst[p];
    *(f16x8*)&Wl[8 * id] = wst[p];
  }
  __syncthreads();

  const int xrow = wm * 32 + la, wrow = wn * 32 + la;
  f16x8 wr[16], xr[16];
#pragma unroll
  for (int t = 0; t < 16; ++t) {
    xr[t] = *(const f16x8*)&Xl[xrow * 256 + 8 * ((2 * t + hi) ^ (xrow & 7))];
    wr[t] = *(const f16x8*)&Wl[wrow * 256 + 8 * ((2 * t + hi) ^ (wrow & 7))];
  }

  const int m0 = e0 + wm * 32;
  const int nb = n0 + wn * 32;
  if (by < 4) {
    f32x16 acc = {};
#pragma unroll
    for (int t = 0; t < 16; ++t) acc = MFMA32_F16(wr[t], xr[t], acc, 0, 0, 0);
#pragma unroll
    for (int i = 0; i < 16; ++i)
      acc[i] += bias[nb + (i & 3) + 8 * (i >> 2) + 4 * hi];
    store16(acc, k16all + (size_t)l * kS * kD + (size_t)(m0 + la) * kD + nb,
            hi);
  } else {
    f32x16 arm = {}, atr = {};
#pragma unroll
    for (int t = 0; t < 16; ++t) {
      arm = MFMA32_F16(wr[t], xr[t], arm, 0, 0, 0);
      atr = MFMA32_F16(xr[t], wr[t], atr, 0, 0, 0);
    }
    const int dv0 = nb - 256;
#pragma unroll
    for (int i = 0; i < 16; ++i)
      arm[i] += bias[nb + (i & 3) + 8 * (i >> 2) + 4 * hi];
    store16(arm, v16all + (size_t)l * kS * kD + (size_t)(m0 + la) * kD + dv0,
            hi);
    const float bv = bias[nb + la];
#pragma unroll
    for (int i = 0; i < 16; ++i) atr[i] += bv;
    store16(atr, vt16all + (size_t)l * kS * kD + (size_t)(dv0 + la) * kS + m0,
            hi);
  }
}

// ---------- dense attention: round-11-verified attn_dense7 (45.6 us) ------
__global__ __launch_bounds__(256, 2) void attn_dense7_k(
    const f16* __restrict__ Q, const f16* __restrict__ Km,
    const f16* __restrict__ Vt,
    f16* __restrict__ numOut, float* __restrict__ denOut) {
  __shared__ __align__(16) f16 Kl[2][64 * 128];  // [key][d], XOR-swizzled
  __shared__ __align__(16) f16 Vl[2][128 * 64];  // [d][key], XOR-swizzled
  const int tid = threadIdx.x;
  const int lane = tid & 63, wid = tid >> 6;
  const int la = lane & 31, hi = lane >> 5;
  const int id = blockIdx.x;
  const int grp = id & 15;
  const int h = grp & 1;
  const int z = grp >> 1;
  const int bx = id >> 4;
  const int q0w = bx * 128 + wid * 32;
  const int sb0 = z * (kS / kNS);
  const int nt = (kS / kNS) / 64;  // 16

  f16x8 qb[8];
#pragma unroll
  for (int kk = 0; kk < 8; ++kk)
    qb[kk] = *(const f16x8*)(Q + (size_t)(q0w + la) * kD + h * kDH + kk * 16 +
                             hi * 8);

  int kSrc[4], kDst[4], vSrc[4], vDst[4];
#pragma unroll
  for (int p = 0; p < 4; ++p) {
    int m = wid * 16 + p * 4 + (lane >> 4);
    int s = lane & 15;
    kSrc[p] = (sb0 + m) * kD + h * kDH + 8 * (s ^ (m & 7));
    kDst[p] = m * 128 + 8 * s;
    int cv = p * 256 + tid;
    int d = cv >> 3, sv = cv & 7;
    vSrc[p] = (h * kDH + d) * kS + sb0 + 8 * (sv ^ (d & 7));
    vDst[p] = d * 64 + 8 * sv;
  }

  f32x16 o0 = {}, o1 = {}, o2 = {}, o3 = {};
  float den = 0.0f;
  f16x8 kst[4], vst[4];

#pragma unroll
  for (int p = 0; p < 4; ++p) {
    kst[p] = *(const f16x8*)(Km + kSrc[p]);
    vst[p] = *(const f16x8*)(Vt + vSrc[p]);
  }
#pragma unroll
  for (int p = 0; p < 4; ++p) {
    *(f16x8*)&Kl[0][kDst[p]] = kst[p];
    *(f16x8*)&Vl[0][vDst[p]] = vst[p];
  }
  __syncthreads();

  for (int t = 0; t < nt; ++t) {
    const int cur = t & 1;
    if (t + 1 < nt) {
#pragma unroll
      for (int p = 0; p < 4; ++p) {
        kst[p] = *(const f16x8*)(Km + kSrc[p] + (t + 1) * 64 * kD);
        vst[p] = *(const f16x8*)(Vt + vSrc[p] + (t + 1) * 64);
      }
    }

    f32x16 st0 = {}, st1 = {};
    __builtin_amdgcn_s_setprio(1);
#pragma unroll
    for (int kk = 0; kk < 8; ++kk) {
      int sl = 8 * ((kk * 2 + hi) ^ (la & 7));
      f16x8 k0 = *(const f16x8*)&Kl[cur][la * 128 + sl];
      f16x8 k1 = *(const f16x8*)&Kl[cur][(32 + la) * 128 + sl];
      st0 = MFMA32_F16(k0, qb[kk], st0, 0, 0, 0);
      st1 = MFMA32_F16(k1, qb[kk], st1, 0, 0, 0);
    }
    __builtin_amdgcn_s_setprio(0);

    f32x16 pe0, pe1;
#pragma unroll
    for (int i = 0; i < 16; ++i) {
      pe0[i] = __expf(st0[i] * kScale);
      pe1[i] = __expf(st1[i] * kScale);
    }
#pragma unroll
    for (int i = 0; i < 16; ++i) den += pe0[i] + pe1[i];

    f16x8 pf[4];
    pf[0] = build_pfrag(pe0[0], pe0[1], pe0[2], pe0[3], pe0[4], pe0[5], pe0[6], pe0[7]);
    pf[1] = build_pfrag(pe0[8], pe0[9], pe0[10], pe0[11], pe0[12], pe0[13], pe0[14], pe0[15]);
    pf[2] = build_pfrag(pe1[0], pe1[1], pe1[2], pe1[3], pe1[4], pe1[5], pe1[6], pe1[7]);
    pf[3] = build_pfrag(pe1[8], pe1[9], pe1[10], pe1[11], pe1[12], pe1[13], pe1[14], pe1[15]);

    __builtin_amdgcn_s_setprio(1);
#pragma unroll
    for (int dt = 0; dt < 4; ++dt) {
      int d = dt * 32 + la;
      f32x16* op = (dt == 0) ? &o0 : (dt == 1) ? &o1 : (dt == 2) ? &o2 : &o3;
#pragma unroll
      for (int ks = 0; ks < 4; ++ks) {
        f16x8 vf = *(const f16x8*)&Vl[cur][d * 64 + 8 * ((ks * 2 + hi) ^ (d & 7))];
        *op = MFMA32_F16(vf, pf[ks], *op, 0, 0, 0);
      }
    }
    __builtin_amdgcn_s_setprio(0);

    if (t + 1 < nt) {
      const int nxt = cur ^ 1;
#pragma unroll
      for (int p = 0; p < 4; ++p) {
        *(f16x8*)&Kl[nxt][kDst[p]] = kst[p];
        *(f16x8*)&Vl[nxt][vDst[p]] = vst[p];
      }
      __syncthreads();
    }
  }

  const size_t nbase = ((size_t)z * kH + h) * kL + q0w;
  const size_t rowb = (nbase + la) * kDH;
#pragma unroll
  for (int dt = 0; dt < 4; ++dt) {
    const f32x16* op = (dt == 0) ? &o0 : (dt == 1) ? &o1 : (dt == 2) ? &o2 : &o3;
    store16(*op, numOut + rowb + dt * 32, hi);
  }
  float dq = den + __shfl_xor(den, 32);
  if (lane < 32)
    denOut[((size_t)z * kH + h) * kL + q0w + lane] = dq;
}

// ---------- fused correction + combine (round-11-verified serial form) ----
__global__ __launch_bounds__(256) void corrcomb_k(
    const unsigned int* __restrict__ loopw, const unsigned char* __restrict__ maskb,
    const int* __restrict__ flags,
    const f16* __restrict__ Q, const f16* __restrict__ Km,
    const f16* __restrict__ V,
    const f16* __restrict__ numb, const float* __restrict__ denb,
    f16* __restrict__ out16) {
  __shared__ float cvL[4][128];
  __shared__ float csL[4];
  const int lane = threadIdx.x & 63;
  const int wid = threadIdx.x >> 6;
  const int w = blockIdx.x * 4 + wid;
  const int f = w >> 1, h = w & 1;
  const int lstride = flags[0];
  const int mstride = flags[1];

  int idx = -1, valid = 0;
  if (lane < 32) {
    idx = (int)loopw[(size_t)(f * 32 + lane) * lstride];
    valid = maskb[(size_t)f * mstride] ? 1 : 0;
  }
#pragma unroll
  for (int j = 0; j < 32; ++j) {
    int oidx = __shfl(idx, j);
    if (lane < 32 && j < lane && oidx == idx) valid = 0;
  }

  const size_t qb = (size_t)f * kD + h * kDH + 2 * lane;
  const float qa = (float)Q[qb];
  const float qbv = (float)Q[qb + 1];
  float s0 = 0.0f, cv0 = 0.0f, cv1 = 0.0f;
  for (int e = 0; e < 32; ++e) {
    int ei = __shfl(idx, e);
    int ev = __shfl(valid, e);
    if (!ev) continue;
    size_t kb = (size_t)ei * kD + h * kDH + 2 * lane;
    float part = qa * (float)Km[kb] + qbv * (float)Km[kb + 1];
#pragma unroll
    for (int m = 1; m < 64; m <<= 1) part += __shfl_xor(part, m);
    float pe = __expf(part * kScale);
    s0 += pe;
    cv0 += pe * (float)V[kb];
    cv1 += pe * (float)V[kb + 1];
  }
  cvL[wid][2 * lane] = cv0;
  cvL[wid][2 * lane + 1] = cv1;
  if (lane == 0) csL[wid] = s0;
  __syncthreads();

#pragma unroll
  for (int e = 0; e < 2; ++e) {
    int idx2 = e * 256 + threadIdx.x;
    int floc = idx2 >> 8;
    int c = idx2 & 255;
    int h2 = c >> 7;
    int d = c & 127;
    int widx = floc * 2 + h2;
    int fabs_ = blockIdx.x * 2 + floc;
    float n = -cvL[widx][d];
    float dn = -csL[widx];
#pragma unroll
    for (int z = 0; z < kNS; ++z) {
      n += (float)numb[((size_t)(z * kH + h2) * kL + fabs_) * kDH + d];
      dn += denb[((size_t)z * kH + h2) * kL + fabs_];
    }
    out16[(size_t)fabs_ * kD + h2 * kDH + d] = (f16)(n / dn);
  }
}

extern "C" void kernel_launch(void* const* d_in, const int* in_sizes, int n_in,
                              void* d_out, int out_size, void* d_ws, size_t ws_size,
                              hipStream_t stream) {
  const unsigned int* loopw = (const unsigned int*)d_in[0];
  const unsigned char* fmask = (const unsigned char*)d_in[1];
  const float* edge = (const float*)d_in[2];
  const float* face = (const float*)d_in[3];
  const float* inw = (const float*)d_in[4];
  const float* inb = (const float*)d_in[5];
  const float* outw = (const float*)d_in[6];
  const float* outb = (const float*)d_in[7];
  float* out = (float*)d_out;

  char* p = (char*)d_ws;
  auto alloc = [&](size_t bytes) {
    char* q = p;
    p += (bytes + 255) & ~(size_t)255;
    return q;
  };
  int* flags = (int*)alloc(256);
  f16* e16 = (f16*)alloc((size_t)kS * kD * 2);
  f16* win16 = (f16*)alloc((size_t)kNL * 3 * kD * kD * 2);
  f16* wout16 = (f16*)alloc((size_t)kNL * kD * kD * 2);
  f16* xa = (f16*)alloc((size_t)kL * kD * 2);
  f16* q16 = (f16*)alloc((size_t)kL * kD * 2);
  f16* ao16 = (f16*)alloc((size_t)kL * kD * 2);
  f16* wqo = (f16*)alloc((size_t)3 * kD * kD * 2);
  float* bprime = (float*)alloc((size_t)3 * kD * 4);
  f16* k16all = (f16*)alloc((size_t)kNL * kS * kD * 2);
  f16* vt16all = (f16*)alloc((size_t)kNL * kS * kD * 2);
  f16* v16all = (f16*)alloc((size_t)kNL * kS * kD * 2);
  f16* numb = (f16*)alloc((size_t)kNS * kH * kL * kDH * 2);
  float* denb = (float*)alloc((size_t)kNS * kH * kL * 4);

  detect_k<<<1, 256, 0, stream>>>(loopw, fmask, flags);
  cvt_all_k<<<1024, 256, 0, stream>>>(edge, face, inw, outw, e16, xa, win16,
                                      wout16);
  compose_k<<<dim3(256, 3), 256, 0, stream>>>(inw, inb, outw, outb, wqo,
                                              bprime);
  kvall4_k<<<4096, 256, 0, stream>>>(e16, win16, inb, k16all, vt16all, v16all);

  for (int l = 0; l < kNL; ++l) {
    const f16* kl = k16all + (size_t)l * kS * kD;
    const f16* vtl = vt16all + (size_t)l * kS * kD;
    const f16* vl = v16all + (size_t)l * kS * kD;
    if (l == 0) {
      gemm32s_k<<<dim3(64, 4), 256, 0, stream>>>(xa, win16, inb, q16, nullptr);
    } else {
      gemm32s_k<<<dim3(64, 4), 256, 0, stream>>>(
          ao16, wqo + (size_t)(l - 1) * kD * kD, bprime + (l - 1) * kD, q16,
          nullptr);
    }
    attn_dense7_k<<<512, 256, 0, stream>>>(q16, kl, vtl, numb, denb);
    corrcomb_k<<<kL / 2, 256, 0, stream>>>(loopw, fmask, flags, q16, kl, vl,
                                           numb, denb, ao16);
  }
  // final out-projection (only layer 3's survives composition), f32 output
  gemm32s_k<<<dim3(64, 4), 256, 0, stream>>>(
      ao16, wout16 + (size_t)3 * kD * kD, outb + 3 * kD, nullptr, out);
}

// Round 20
// 356.068 us; speedup vs baseline: 1.1570x; 1.0280x over previous
//
#include <hip/hip_runtime.h>
#include <math.h>

typedef _Float16 f16;
typedef _Float16 f16x4 __attribute__((ext_vector_type(4)));
typedef _Float16 f16x8 __attribute__((ext_vector_type(8)));
typedef float f32x4 __attribute__((ext_vector_type(4)));
typedef float f32x16 __attribute__((ext_vector_type(16)));

#define MFMA32_F16 __builtin_amdgcn_mfma_f32_32x32x16_f16

namespace {
constexpr int kL = 4096;   // faces (queries)
constexpr int kS = 8192;   // edges (keys/values)
constexpr int kD = 256;    // embed dim
constexpr int kH = 2;      // heads
constexpr int kDH = 128;   // head dim
constexpr int kNL = 4;     // layers
constexpr int kNS = 8;     // S-dim splits in dense attention
constexpr float kScale = 0.08838834764831845f;  // 1/sqrt(128)
}

// ---------- fused prologue: cvt (blocks 0-1023) | detect (1024) |
// ---------- compose wqo_l = wq_l.wo_{l-1} (blocks 1025-1792) ---------------
// All three are mutually independent (compose reads raw f32 weights).
__global__ __launch_bounds__(256) void prologue_k(
    const float* __restrict__ edge, const float* __restrict__ face,
    const float* __restrict__ inw, const float* __restrict__ inb,
    const float* __restrict__ outw, const float* __restrict__ outb,
    const unsigned int* __restrict__ loopw, const unsigned char* __restrict__ maskb,
    f16* __restrict__ e16, f16* __restrict__ xa,
    f16* __restrict__ win16, f16* __restrict__ wout16,
    int* __restrict__ flags, f16* __restrict__ wqo,
    float* __restrict__ bprime) {
  const int bid = blockIdx.x;
  if (bid < 1024) {
    for (int i = bid * 256 + threadIdx.x; i < 1048576; i += 1024 * 256) {
      const float* src;
      f16* dst;
      int off;
      if (i < 524288) { src = edge; dst = e16; off = i; }
      else if (i < 786432) { src = face; dst = xa; off = i - 524288; }
      else if (i < 983040) { src = inw; dst = win16; off = i - 786432; }
      else { src = outw; dst = wout16; off = i - 983040; }
      float4 v = *(const float4*)(src + 4 * (size_t)off);
      f16x4 h;
      h[0] = (f16)v.x; h[1] = (f16)v.y; h[2] = (f16)v.z; h[3] = (f16)v.w;
      *(f16x4*)(dst + 4 * (size_t)off) = h;
    }
  } else if (bid == 1024) {
    __shared__ unsigned int s[3];
    if (threadIdx.x < 3) s[threadIdx.x] = 0;
    __syncthreads();
    unsigned int orodd = 0;
    for (int i = 1 + 2 * threadIdx.x; i < 2048; i += 512) orodd |= loopw[i];
    unsigned int nz1 = 0, nz4 = 0;
    for (int i = threadIdx.x; i < 512; i += 256) {
      unsigned char b = maskb[i];
      if ((i & 3) != 0) nz1 |= b;
      if ((i & 7) == 4) nz4 |= b;
    }
    atomicOr(&s[0], orodd);
    atomicOr(&s[1], nz1);
    atomicOr(&s[2], nz4);
    __syncthreads();
    if (threadIdx.x == 0) {
      flags[0] = (s[0] == 0) ? 2 : 1;
      flags[1] = s[1] ? 1 : (s[2] ? 4 : 8);
    }
  } else {
    const int cb = bid - 1025;     // 0..767
    const int i = cb & 255;        // output row
    const int lc = cb >> 8;        // 0..2 -> layer l = lc+1
    const int j = threadIdx.x;     // output col
    const int l = lc + 1;
    const float* wq = inw + (size_t)l * 3 * kD * kD;
    const float* wo = outw + (size_t)lc * kD * kD;
    float acc = 0.0f;
    for (int k = 0; k < kD; ++k)
      acc += wq[i * kD + k] * wo[k * kD + j];
    wqo[((size_t)lc * kD + i) * kD + j] = (f16)acc;

    float t = wq[i * kD + j] * outb[lc * kD + j];
    __shared__ float red[4];
#pragma unroll
    for (int m = 1; m < 64; m <<= 1) t += __shfl_xor(t, m);
    if ((threadIdx.x & 63) == 0) red[threadIdx.x >> 6] = t;
    __syncthreads();
    if (threadIdx.x == 0)
      bprime[lc * kD + i] =
          red[0] + red[1] + red[2] + red[3] + inb[l * 3 * kD + i];
  }
}

// ---------- helpers: pkh / pswap / verified 16-f32 -> 2x f16x8 epilogue ----
__device__ __forceinline__ unsigned pkh(float a, float b) {
  auto h2 = __builtin_amdgcn_cvt_pkrtz(a, b);
  return __builtin_bit_cast(unsigned, h2);
}
__device__ __forceinline__ void pswap(unsigned a, unsigned b, unsigned& x,
                                      unsigned& y) {
  typedef int i32x2 __attribute__((ext_vector_type(2)));
  i32x2 rr = __builtin_amdgcn_permlane32_swap((int)a, (int)b, false, false);
  x = (unsigned)rr[0];
  y = (unsigned)rr[1];
}
__device__ __forceinline__ f16x8 build_pfrag(float p0, float p1, float p2,
                                             float p3, float p4, float p5,
                                             float p6, float p7) {
  unsigned a0 = pkh(p0, p1), b0 = pkh(p4, p5);
  unsigned a1 = pkh(p2, p3), b1 = pkh(p6, p7);
  unsigned w0, w1, w2, w3;
  pswap(a0, b0, w0, w2);
  pswap(a1, b1, w1, w3);
  union { unsigned u[4]; f16x8 v; } r;
  r.u[0] = w0; r.u[1] = w1; r.u[2] = w2; r.u[3] = w3;
  return r.v;
}
// Store a 32x32 C-fragment row (f32x16, col=lane&31, row=(i&3)+8*(i>>2)+4*hi)
// as two f16x8 stores at base+hi*8 and base+16+hi*8 (round-10/11-verified).
__device__ __forceinline__ void store16(const f32x16& a, f16* base, int hi) {
  unsigned u01 = pkh(a[0], a[1]), u23 = pkh(a[2], a[3]);
  unsigned u89 = pkh(a[4], a[5]), uab = pkh(a[6], a[7]);
  unsigned w0, w1, w2, w3;
  pswap(u01, u89, w0, w2);
  pswap(u23, uab, w1, w3);
  union { unsigned u[4]; f16x8 v; } r1;
  r1.u[0] = w0; r1.u[1] = w1; r1.u[2] = w2; r1.u[3] = w3;
  *(f16x8*)(base + hi * 8) = r1.v;
  unsigned v01 = pkh(a[8], a[9]), v23 = pkh(a[10], a[11]);
  unsigned v89 = pkh(a[12], a[13]), vab = pkh(a[14], a[15]);
  unsigned x0, x1, x2, x3;
  pswap(v01, v89, x0, x2);
  pswap(v23, vab, x1, x3);
  union { unsigned u[4]; f16x8 v; } r2;
  r2.u[0] = x0; r2.u[1] = x1; r2.u[2] = x2; r2.u[3] = x3;
  *(f16x8*)(base + 16 + hi * 8) = r2.v;
}

// ---------- 32x32-MFMA GEMM with LDS-staged operands (kvall4 pattern) ------
__global__ __launch_bounds__(256) void gemm32s_k(
    const f16* __restrict__ X, const f16* __restrict__ W,
    const float* __restrict__ bias, f16* __restrict__ C16,
    float* __restrict__ C32) {
  __shared__ __align__(16) f16 Xl[64 * 256];
  __shared__ __align__(16) f16 Wl[64 * 256];
  const int tid = threadIdx.x;
  const int lane = tid & 63, wid = tid >> 6;
  const int la = lane & 31, hi = lane >> 5;
  const int wm = wid & 1, wn = wid >> 1;
  const int m0b = blockIdx.x * 64, n0b = blockIdx.y * 64;

  f16x8 xst[8], wst[8];
#pragma unroll
  for (int p = 0; p < 8; ++p) {
    int id = p * 256 + tid;
    int row = id >> 5, s = id & 31;
    xst[p] = *(const f16x8*)(X + (size_t)(m0b + row) * kD + 8 * (s ^ (row & 7)));
    wst[p] = *(const f16x8*)(W + (size_t)(n0b + row) * kD + 8 * (s ^ (row & 7)));
  }
#pragma unroll
  for (int p = 0; p < 8; ++p) {
    int id = p * 256 + tid;
    *(f16x8*)&Xl[8 * id] = xst[p];
    *(f16x8*)&Wl[8 * id] = wst[p];
  }
  __syncthreads();

  const int xrow = wm * 32 + la, wrow = wn * 32 + la;
  f16x8 wr[16], xr[16];
#pragma unroll
  for (int t = 0; t < 16; ++t) {
    xr[t] = *(const f16x8*)&Xl[xrow * 256 + 8 * ((2 * t + hi) ^ (xrow & 7))];
    wr[t] = *(const f16x8*)&Wl[wrow * 256 + 8 * ((2 * t + hi) ^ (wrow & 7))];
  }

  const int m0 = m0b + wm * 32;
  const int n0 = n0b + wn * 32;
  f32x16 acc = {};
#pragma unroll
  for (int t = 0; t < 16; ++t) acc = MFMA32_F16(wr[t], xr[t], acc, 0, 0, 0);
#pragma unroll
  for (int i = 0; i < 16; ++i)
    acc[i] += bias[n0 + (i & 3) + 8 * (i >> 2) + 4 * hi];
  if (C16) store16(acc, C16 + (size_t)(m0 + la) * kD + n0, hi);
  if (C32) {
    float* row = C32 + (size_t)(m0 + la) * kD + n0;
    float4 f0 = {acc[0], acc[1], acc[2], acc[3]};
    float4 f1 = {acc[4], acc[5], acc[6], acc[7]};
    float4 f2 = {acc[8], acc[9], acc[10], acc[11]};
    float4 f3 = {acc[12], acc[13], acc[14], acc[15]};
    *(float4*)(row + 4 * hi) = f0;
    *(float4*)(row + 8 + 4 * hi) = f1;
    *(float4*)(row + 16 + 4 * hi) = f2;
    *(float4*)(row + 24 + 4 * hi) = f3;
  }
}

// ---------- all-layer K/V projection: LDS-staged operands (round-18) -------
__global__ __launch_bounds__(256) void kvall4_k(
    const f16* __restrict__ e16, const f16* __restrict__ win16,
    const float* __restrict__ inb,
    f16* __restrict__ k16all, f16* __restrict__ vt16all,
    f16* __restrict__ v16all) {
  __shared__ __align__(16) f16 Xl[64 * 256];
  __shared__ __align__(16) f16 Wl[64 * 256];
  const int tid = threadIdx.x;
  const int lane = tid & 63, wid = tid >> 6;
  const int la = lane & 31, hi = lane >> 5;
  const int wm = wid & 1, wn = wid >> 1;
  const int bid = blockIdx.x;
  const int l = bid >> 10;
  const int tt = bid & 1023;
  const int bx = tt & 127, by = tt >> 7;  // by 0-3: K cols, 4-7: V cols
  const int e0 = bx * 64, n0 = by * 64;
  const f16* W = win16 + (size_t)l * 3 * kD * kD + (size_t)kD * kD;
  const float* bias = inb + (size_t)l * 3 * kD + kD;

  f16x8 xst[8], wst[8];
#pragma unroll
  for (int p = 0; p < 8; ++p) {
    int id = p * 256 + tid;
    int row = id >> 5, s = id & 31;
    xst[p] = *(const f16x8*)(e16 + (size_t)(e0 + row) * kD + 8 * (s ^ (row & 7)));
    wst[p] = *(const f16x8*)(W + (size_t)(n0 + row) * kD + 8 * (s ^ (row & 7)));
  }
#pragma unroll
  for (int p = 0; p < 8; ++p) {
    int id = p * 256 + tid;
    *(f16x8*)&Xl[8 * id] = xst[p];
    *(f16x8*)&Wl[8 * id] = wst[p];
  }
  __syncthreads();

  const int xrow = wm * 32 + la, wrow = wn * 32 + la;
  f16x8 wr[16], xr[16];
#pragma unroll
  for (int t = 0; t < 16; ++t) {
    xr[t] = *(const f16x8*)&Xl[xrow * 256 + 8 * ((2 * t + hi) ^ (xrow & 7))];
    wr[t] = *(const f16x8*)&Wl[wrow * 256 + 8 * ((2 * t + hi) ^ (wrow & 7))];
  }

  const int m0 = e0 + wm * 32;
  const int nb = n0 + wn * 32;
  if (by < 4) {
    f32x16 acc = {};
#pragma unroll
    for (int t = 0; t < 16; ++t) acc = MFMA32_F16(wr[t], xr[t], acc, 0, 0, 0);
#pragma unroll
    for (int i = 0; i < 16; ++i)
      acc[i] += bias[nb + (i & 3) + 8 * (i >> 2) + 4 * hi];
    store16(acc, k16all + (size_t)l * kS * kD + (size_t)(m0 + la) * kD + nb,
            hi);
  } else {
    f32x16 arm = {}, atr = {};
#pragma unroll
    for (int t = 0; t < 16; ++t) {
      arm = MFMA32_F16(wr[t], xr[t], arm, 0, 0, 0);
      atr = MFMA32_F16(xr[t], wr[t], atr, 0, 0, 0);
    }
    const int dv0 = nb - 256;
#pragma unroll
    for (int i = 0; i < 16; ++i)
      arm[i] += bias[nb + (i & 3) + 8 * (i >> 2) + 4 * hi];
    store16(arm, v16all + (size_t)l * kS * kD + (size_t)(m0 + la) * kD + dv0,
            hi);
    const float bv = bias[nb + la];
#pragma unroll
    for (int i = 0; i < 16; ++i) atr[i] += bv;
    store16(atr, vt16all + (size_t)l * kS * kD + (size_t)(dv0 + la) * kS + m0,
            hi);
  }
}

// ---------- dense attention: round-11-verified structure; den via MFMA -----
// den[q] = sum_k P[k][q] computed by dacc += MFMA(ones, pf[ks]) (A=ones ->
// every C row = den). Replaces 32 VALU adds/step + final shfl; num and den
// now both derive from the same f16-quantized P (consistency bonus).
__global__ __launch_bounds__(256, 2) void attn_dense7_k(
    const f16* __restrict__ Q, const f16* __restrict__ Km,
    const f16* __restrict__ Vt,
    f16* __restrict__ numOut, float* __restrict__ denOut) {
  __shared__ __align__(16) f16 Kl[2][64 * 128];  // [key][d], XOR-swizzled
  __shared__ __align__(16) f16 Vl[2][128 * 64];  // [d][key], XOR-swizzled
  const int tid = threadIdx.x;
  const int lane = tid & 63, wid = tid >> 6;
  const int la = lane & 31, hi = lane >> 5;
  const int id = blockIdx.x;
  const int grp = id & 15;
  const int h = grp & 1;
  const int z = grp >> 1;
  const int bx = id >> 4;
  const int q0w = bx * 128 + wid * 32;
  const int sb0 = z * (kS / kNS);
  const int nt = (kS / kNS) / 64;  // 16

  f16x8 qb[8];
#pragma unroll
  for (int kk = 0; kk < 8; ++kk)
    qb[kk] = *(const f16x8*)(Q + (size_t)(q0w + la) * kD + h * kDH + kk * 16 +
                             hi * 8);

  int kSrc[4], kDst[4], vSrc[4], vDst[4];
#pragma unroll
  for (int p = 0; p < 4; ++p) {
    int m = wid * 16 + p * 4 + (lane >> 4);
    int s = lane & 15;
    kSrc[p] = (sb0 + m) * kD + h * kDH + 8 * (s ^ (m & 7));
    kDst[p] = m * 128 + 8 * s;
    int cv = p * 256 + tid;
    int d = cv >> 3, sv = cv & 7;
    vSrc[p] = (h * kDH + d) * kS + sb0 + 8 * (sv ^ (d & 7));
    vDst[p] = d * 64 + 8 * sv;
  }

  f32x16 o0 = {}, o1 = {}, o2 = {}, o3 = {}, dacc = {};
  const f16x8 ones = {(f16)1.0f, (f16)1.0f, (f16)1.0f, (f16)1.0f,
                      (f16)1.0f, (f16)1.0f, (f16)1.0f, (f16)1.0f};
  f16x8 kst[4], vst[4];

#pragma unroll
  for (int p = 0; p < 4; ++p) {
    kst[p] = *(const f16x8*)(Km + kSrc[p]);
    vst[p] = *(const f16x8*)(Vt + vSrc[p]);
  }
#pragma unroll
  for (int p = 0; p < 4; ++p) {
    *(f16x8*)&Kl[0][kDst[p]] = kst[p];
    *(f16x8*)&Vl[0][vDst[p]] = vst[p];
  }
  __syncthreads();

  for (int t = 0; t < nt; ++t) {
    const int cur = t & 1;
    if (t + 1 < nt) {
#pragma unroll
      for (int p = 0; p < 4; ++p) {
        kst[p] = *(const f16x8*)(Km + kSrc[p] + (t + 1) * 64 * kD);
        vst[p] = *(const f16x8*)(Vt + vSrc[p] + (t + 1) * 64);
      }
    }

    f32x16 st0 = {}, st1 = {};
    __builtin_amdgcn_s_setprio(1);
#pragma unroll
    for (int kk = 0; kk < 8; ++kk) {
      int sl = 8 * ((kk * 2 + hi) ^ (la & 7));
      f16x8 k0 = *(const f16x8*)&Kl[cur][la * 128 + sl];
      f16x8 k1 = *(const f16x8*)&Kl[cur][(32 + la) * 128 + sl];
      st0 = MFMA32_F16(k0, qb[kk], st0, 0, 0, 0);
      st1 = MFMA32_F16(k1, qb[kk], st1, 0, 0, 0);
    }
    __builtin_amdgcn_s_setprio(0);

    f32x16 pe0, pe1;
#pragma unroll
    for (int i = 0; i < 16; ++i) {
      pe0[i] = __expf(st0[i] * kScale);
      pe1[i] = __expf(st1[i] * kScale);
    }

    f16x8 pf[4];
    pf[0] = build_pfrag(pe0[0], pe0[1], pe0[2], pe0[3], pe0[4], pe0[5], pe0[6], pe0[7]);
    pf[1] = build_pfrag(pe0[8], pe0[9], pe0[10], pe0[11], pe0[12], pe0[13], pe0[14], pe0[15]);
    pf[2] = build_pfrag(pe1[0], pe1[1], pe1[2], pe1[3], pe1[4], pe1[5], pe1[6], pe1[7]);
    pf[3] = build_pfrag(pe1[8], pe1[9], pe1[10], pe1[11], pe1[12], pe1[13], pe1[14], pe1[15]);

    __builtin_amdgcn_s_setprio(1);
#pragma unroll
    for (int dt = 0; dt < 4; ++dt) {
      int d = dt * 32 + la;
      f32x16* op = (dt == 0) ? &o0 : (dt == 1) ? &o1 : (dt == 2) ? &o2 : &o3;
#pragma unroll
      for (int ks = 0; ks < 4; ++ks) {
        f16x8 vf = *(const f16x8*)&Vl[cur][d * 64 + 8 * ((ks * 2 + hi) ^ (d & 7))];
        *op = MFMA32_F16(vf, pf[ks], *op, 0, 0, 0);
      }
    }
#pragma unroll
    for (int ks = 0; ks < 4; ++ks)
      dacc = MFMA32_F16(ones, pf[ks], dacc, 0, 0, 0);
    __builtin_amdgcn_s_setprio(0);

    if (t + 1 < nt) {
      const int nxt = cur ^ 1;
#pragma unroll
      for (int p = 0; p < 4; ++p) {
        *(f16x8*)&Kl[nxt][kDst[p]] = kst[p];
        *(f16x8*)&Vl[nxt][vDst[p]] = vst[p];
      }
      __syncthreads();
    }
  }

  const size_t nbase = ((size_t)z * kH + h) * kL + q0w;
  const size_t rowb = (nbase + la) * kDH;
#pragma unroll
  for (int dt = 0; dt < 4; ++dt) {
    const f32x16* op = (dt == 0) ? &o0 : (dt == 1) ? &o1 : (dt == 2) ? &o2 : &o3;
    store16(*op, numOut + rowb + dt * 32, hi);
  }
  if (lane < 32)
    denOut[((size_t)z * kH + h) * kL + q0w + lane] = dacc[0];
}

// ---------- fused correction + combine (round-11-verified serial form) ----
__global__ __launch_bounds__(256) void corrcomb_k(
    const unsigned int* __restrict__ loopw, const unsigned char* __restrict__ maskb,
    const int* __restrict__ flags,
    const f16* __restrict__ Q, const f16* __restrict__ Km,
    const f16* __restrict__ V,
    const f16* __restrict__ numb, const float* __restrict__ denb,
    f16* __restrict__ out16) {
  __shared__ float cvL[4][128];
  __shared__ float csL[4];
  const int lane = threadIdx.x & 63;
  const int wid = threadIdx.x >> 6;
  const int w = blockIdx.x * 4 + wid;
  const int f = w >> 1, h = w & 1;
  const int lstride = flags[0];
  const int mstride = flags[1];

  int idx = -1, valid = 0;
  if (lane < 32) {
    idx = (int)loopw[(size_t)(f * 32 + lane) * lstride];
    valid = maskb[(size_t)f * mstride] ? 1 : 0;
  }
#pragma unroll
  for (int j = 0; j < 32; ++j) {
    int oidx = __shfl(idx, j);
    if (lane < 32 && j < lane && oidx == idx) valid = 0;
  }

  const size_t qb = (size_t)f * kD + h * kDH + 2 * lane;
  const float qa = (float)Q[qb];
  const float qbv = (float)Q[qb + 1];
  float s0 = 0.0f, cv0 = 0.0f, cv1 = 0.0f;
  for (int e = 0; e < 32; ++e) {
    int ei = __shfl(idx, e);
    int ev = __shfl(valid, e);
    if (!ev) continue;
    size_t kb = (size_t)ei * kD + h * kDH + 2 * lane;
    float part = qa * (float)Km[kb] + qbv * (float)Km[kb + 1];
#pragma unroll
    for (int m = 1; m < 64; m <<= 1) part += __shfl_xor(part, m);
    float pe = __expf(part * kScale);
    s0 += pe;
    cv0 += pe * (float)V[kb];
    cv1 += pe * (float)V[kb + 1];
  }
  cvL[wid][2 * lane] = cv0;
  cvL[wid][2 * lane + 1] = cv1;
  if (lane == 0) csL[wid] = s0;
  __syncthreads();

#pragma unroll
  for (int e = 0; e < 2; ++e) {
    int idx2 = e * 256 + threadIdx.x;
    int floc = idx2 >> 8;
    int c = idx2 & 255;
    int h2 = c >> 7;
    int d = c & 127;
    int widx = floc * 2 + h2;
    int fabs_ = blockIdx.x * 2 + floc;
    float n = -cvL[widx][d];
    float dn = -csL[widx];
#pragma unroll
    for (int z = 0; z < kNS; ++z) {
      n += (float)numb[((size_t)(z * kH + h2) * kL + fabs_) * kDH + d];
      dn += denb[((size_t)z * kH + h2) * kL + fabs_];
    }
    out16[(size_t)fabs_ * kD + h2 * kDH + d] = (f16)(n / dn);
  }
}

extern "C" void kernel_launch(void* const* d_in, const int* in_sizes, int n_in,
                              void* d_out, int out_size, void* d_ws, size_t ws_size,
                              hipStream_t stream) {
  const unsigned int* loopw = (const unsigned int*)d_in[0];
  const unsigned char* fmask = (const unsigned char*)d_in[1];
  const float* edge = (const float*)d_in[2];
  const float* face = (const float*)d_in[3];
  const float* inw = (const float*)d_in[4];
  const float* inb = (const float*)d_in[5];
  const float* outw = (const float*)d_in[6];
  const float* outb = (const float*)d_in[7];
  float* out = (float*)d_out;

  char* p = (char*)d_ws;
  auto alloc = [&](size_t bytes) {
    char* q = p;
    p += (bytes + 255) & ~(size_t)255;
    return q;
  };
  int* flags = (int*)alloc(256);
  f16* e16 = (f16*)alloc((size_t)kS * kD * 2);
  f16* win16 = (f16*)alloc((size_t)kNL * 3 * kD * kD * 2);
  f16* wout16 = (f16*)alloc((size_t)kNL * kD * kD * 2);
  f16* xa = (f16*)alloc((size_t)kL * kD * 2);
  f16* q16 = (f16*)alloc((size_t)kL * kD * 2);
  f16* ao16 = (f16*)alloc((size_t)kL * kD * 2);
  f16* wqo = (f16*)alloc((size_t)3 * kD * kD * 2);
  float* bprime = (float*)alloc((size_t)3 * kD * 4);
  f16* k16all = (f16*)alloc((size_t)kNL * kS * kD * 2);
  f16* vt16all = (f16*)alloc((size_t)kNL * kS * kD * 2);
  f16* v16all = (f16*)alloc((size_t)kNL * kS * kD * 2);
  f16* numb = (f16*)alloc((size_t)kNS * kH * kL * kDH * 2);
  float* denb = (float*)alloc((size_t)kNS * kH * kL * 4);

  prologue_k<<<1793, 256, 0, stream>>>(edge, face, inw, inb, outw, outb,
                                       loopw, fmask, e16, xa, win16, wout16,
                                       flags, wqo, bprime);
  kvall4_k<<<4096, 256, 0, stream>>>(e16, win16, inb, k16all, vt16all, v16all);

  for (int l = 0; l < kNL; ++l) {
    const f16* kl = k16all + (size_t)l * kS * kD;
    const f16* vtl = vt16all + (size_t)l * kS * kD;
    const f16* vl = v16all + (size_t)l * kS * kD;
    if (l == 0) {
      gemm32s_k<<<dim3(64, 4), 256, 0, stream>>>(xa, win16, inb, q16, nullptr);
    } else {
      gemm32s_k<<<dim3(64, 4), 256, 0, stream>>>(
          ao16, wqo + (size_t)(l - 1) * kD * kD, bprime + (l - 1) * kD, q16,
          nullptr);
    }
    attn_dense7_k<<<512, 256, 0, stream>>>(q16, kl, vtl, numb, denb);
    corrcomb_k<<<kL / 2, 256, 0, stream>>>(loopw, fmask, flags, q16, kl, vl,
                                           numb, denb, ao16);
  }
  // final out-projection (only layer 3's survives composition), f32 output
  gemm32s_k<<<dim3(64, 4), 256, 0, stream>>>(
      ao16, wout16 + (size_t)3 * kD * kD, outb + 3 * kD, nullptr, out);
}

// Round 21
// 349.565 us; speedup vs baseline: 1.1785x; 1.0186x over previous
//
#include <hip/hip_runtime.h>
#include <math.h>

typedef _Float16 f16;
typedef _Float16 f16x2 __attribute__((ext_vector_type(2)));
typedef _Float16 f16x4 __attribute__((ext_vector_type(4)));
typedef _Float16 f16x8 __attribute__((ext_vector_type(8)));
typedef float f32x4 __attribute__((ext_vector_type(4)));
typedef float f32x16 __attribute__((ext_vector_type(16)));

#define MFMA32_F16 __builtin_amdgcn_mfma_f32_32x32x16_f16

namespace {
constexpr int kL = 4096;   // faces (queries)
constexpr int kS = 8192;   // edges (keys/values)
constexpr int kD = 256;    // embed dim
constexpr int kH = 2;      // heads
constexpr int kDH = 128;   // head dim
constexpr int kNL = 4;     // layers
constexpr int kNS = 8;     // S-dim splits in dense attention
constexpr float kScale = 0.08838834764831845f;  // 1/sqrt(128)
}

// ---------- fused prologue: cvt (blocks 0-1023) | detect (1024) |
// ---------- compose wqo_l = wq_l.wo_{l-1} (blocks 1025-1792) ---------------
__global__ __launch_bounds__(256) void prologue_k(
    const float* __restrict__ edge, const float* __restrict__ face,
    const float* __restrict__ inw, const float* __restrict__ inb,
    const float* __restrict__ outw, const float* __restrict__ outb,
    const unsigned int* __restrict__ loopw, const unsigned char* __restrict__ maskb,
    f16* __restrict__ e16, f16* __restrict__ xa,
    f16* __restrict__ win16, f16* __restrict__ wout16,
    int* __restrict__ flags, f16* __restrict__ wqo,
    float* __restrict__ bprime) {
  const int bid = blockIdx.x;
  if (bid < 1024) {
    for (int i = bid * 256 + threadIdx.x; i < 1048576; i += 1024 * 256) {
      const float* src;
      f16* dst;
      int off;
      if (i < 524288) { src = edge; dst = e16; off = i; }
      else if (i < 786432) { src = face; dst = xa; off = i - 524288; }
      else if (i < 983040) { src = inw; dst = win16; off = i - 786432; }
      else { src = outw; dst = wout16; off = i - 983040; }
      float4 v = *(const float4*)(src + 4 * (size_t)off);
      f16x4 h;
      h[0] = (f16)v.x; h[1] = (f16)v.y; h[2] = (f16)v.z; h[3] = (f16)v.w;
      *(f16x4*)(dst + 4 * (size_t)off) = h;
    }
  } else if (bid == 1024) {
    __shared__ unsigned int s[3];
    if (threadIdx.x < 3) s[threadIdx.x] = 0;
    __syncthreads();
    unsigned int orodd = 0;
    for (int i = 1 + 2 * threadIdx.x; i < 2048; i += 512) orodd |= loopw[i];
    unsigned int nz1 = 0, nz4 = 0;
    for (int i = threadIdx.x; i < 512; i += 256) {
      unsigned char b = maskb[i];
      if ((i & 3) != 0) nz1 |= b;
      if ((i & 7) == 4) nz4 |= b;
    }
    atomicOr(&s[0], orodd);
    atomicOr(&s[1], nz1);
    atomicOr(&s[2], nz4);
    __syncthreads();
    if (threadIdx.x == 0) {
      flags[0] = (s[0] == 0) ? 2 : 1;
      flags[1] = s[1] ? 1 : (s[2] ? 4 : 8);
    }
  } else {
    const int cb = bid - 1025;     // 0..767
    const int i = cb & 255;        // output row
    const int lc = cb >> 8;        // 0..2 -> layer l = lc+1
    const int j = threadIdx.x;     // output col
    const int l = lc + 1;
    const float* wq = inw + (size_t)l * 3 * kD * kD;
    const float* wo = outw + (size_t)lc * kD * kD;
    float acc = 0.0f;
    for (int k = 0; k < kD; ++k)
      acc += wq[i * kD + k] * wo[k * kD + j];
    wqo[((size_t)lc * kD + i) * kD + j] = (f16)acc;

    float t = wq[i * kD + j] * outb[lc * kD + j];
    __shared__ float red[4];
#pragma unroll
    for (int m = 1; m < 64; m <<= 1) t += __shfl_xor(t, m);
    if ((threadIdx.x & 63) == 0) red[threadIdx.x >> 6] = t;
    __syncthreads();
    if (threadIdx.x == 0)
      bprime[lc * kD + i] =
          red[0] + red[1] + red[2] + red[3] + inb[l * 3 * kD + i];
  }
}

// ---------- helpers: pkh / pswap / verified 16-f32 -> 2x f16x8 epilogue ----
__device__ __forceinline__ unsigned pkh(float a, float b) {
  auto h2 = __builtin_amdgcn_cvt_pkrtz(a, b);
  return __builtin_bit_cast(unsigned, h2);
}
__device__ __forceinline__ void pswap(unsigned a, unsigned b, unsigned& x,
                                      unsigned& y) {
  typedef int i32x2 __attribute__((ext_vector_type(2)));
  i32x2 rr = __builtin_amdgcn_permlane32_swap((int)a, (int)b, false, false);
  x = (unsigned)rr[0];
  y = (unsigned)rr[1];
}
__device__ __forceinline__ f16x8 build_pfrag(float p0, float p1, float p2,
                                             float p3, float p4, float p5,
                                             float p6, float p7) {
  unsigned a0 = pkh(p0, p1), b0 = pkh(p4, p5);
  unsigned a1 = pkh(p2, p3), b1 = pkh(p6, p7);
  unsigned w0, w1, w2, w3;
  pswap(a0, b0, w0, w2);
  pswap(a1, b1, w1, w3);
  union { unsigned u[4]; f16x8 v; } r;
  r.u[0] = w0; r.u[1] = w1; r.u[2] = w2; r.u[3] = w3;
  return r.v;
}
// Store a 32x32 C-fragment row (f32x16, col=lane&31, row=(i&3)+8*(i>>2)+4*hi)
// as two f16x8 stores at base+hi*8 and base+16+hi*8 (round-10/11-verified).
__device__ __forceinline__ void store16(const f32x16& a, f16* base, int hi) {
  unsigned u01 = pkh(a[0], a[1]), u23 = pkh(a[2], a[3]);
  unsigned u89 = pkh(a[4], a[5]), uab = pkh(a[6], a[7]);
  unsigned w0, w1, w2, w3;
  pswap(u01, u89, w0, w2);
  pswap(u23, uab, w1, w3);
  union { unsigned u[4]; f16x8 v; } r1;
  r1.u[0] = w0; r1.u[1] = w1; r1.u[2] = w2; r1.u[3] = w3;
  *(f16x8*)(base + hi * 8) = r1.v;
  unsigned v01 = pkh(a[8], a[9]), v23 = pkh(a[10], a[11]);
  unsigned v89 = pkh(a[12], a[13]), vab = pkh(a[14], a[15]);
  unsigned x0, x1, x2, x3;
  pswap(v01, v89, x0, x2);
  pswap(v23, vab, x1, x3);
  union { unsigned u[4]; f16x8 v; } r2;
  r2.u[0] = x0; r2.u[1] = x1; r2.u[2] = x2; r2.u[3] = x3;
  *(f16x8*)(base + 16 + hi * 8) = r2.v;
}

// ---------- 32x32-MFMA GEMM with LDS-staged operands (kvall4 pattern) ------
__global__ __launch_bounds__(256) void gemm32s_k(
    const f16* __restrict__ X, const f16* __restrict__ W,
    const float* __restrict__ bias, f16* __restrict__ C16,
    float* __restrict__ C32) {
  __shared__ __align__(16) f16 Xl[64 * 256];
  __shared__ __align__(16) f16 Wl[64 * 256];
  const int tid = threadIdx.x;
  const int lane = tid & 63, wid = tid >> 6;
  const int la = lane & 31, hi = lane >> 5;
  const int wm = wid & 1, wn = wid >> 1;
  const int m0b = blockIdx.x * 64, n0b = blockIdx.y * 64;

  f16x8 xst[8], wst[8];
#pragma unroll
  for (int p = 0; p < 8; ++p) {
    int id = p * 256 + tid;
    int row = id >> 5, s = id & 31;
    xst[p] = *(const f16x8*)(X + (size_t)(m0b + row) * kD + 8 * (s ^ (row & 7)));
    wst[p] = *(const f16x8*)(W + (size_t)(n0b + row) * kD + 8 * (s ^ (row & 7)));
  }
#pragma unroll
  for (int p = 0; p < 8; ++p) {
    int id = p * 256 + tid;
    *(f16x8*)&Xl[8 * id] = xst[p];
    *(f16x8*)&Wl[8 * id] = wst[p];
  }
  __syncthreads();

  const int xrow = wm * 32 + la, wrow = wn * 32 + la;
  f16x8 wr[16], xr[16];
#pragma unroll
  for (int t = 0; t < 16; ++t) {
    xr[t] = *(const f16x8*)&Xl[xrow * 256 + 8 * ((2 * t + hi) ^ (xrow & 7))];
    wr[t] = *(const f16x8*)&Wl[wrow * 256 + 8 * ((2 * t + hi) ^ (wrow & 7))];
  }

  const int m0 = m0b + wm * 32;
  const int n0 = n0b + wn * 32;
  f32x16 acc = {};
#pragma unroll
  for (int t = 0; t < 16; ++t) acc = MFMA32_F16(wr[t], xr[t], acc, 0, 0, 0);
#pragma unroll
  for (int i = 0; i < 16; ++i)
    acc[i] += bias[n0 + (i & 3) + 8 * (i >> 2) + 4 * hi];
  if (C16) store16(acc, C16 + (size_t)(m0 + la) * kD + n0, hi);
  if (C32) {
    float* row = C32 + (size_t)(m0 + la) * kD + n0;
    float4 f0 = {acc[0], acc[1], acc[2], acc[3]};
    float4 f1 = {acc[4], acc[5], acc[6], acc[7]};
    float4 f2 = {acc[8], acc[9], acc[10], acc[11]};
    float4 f3 = {acc[12], acc[13], acc[14], acc[15]};
    *(float4*)(row + 4 * hi) = f0;
    *(float4*)(row + 8 + 4 * hi) = f1;
    *(float4*)(row + 16 + 4 * hi) = f2;
    *(float4*)(row + 24 + 4 * hi) = f3;
  }
}

// ---------- all-layer K/V projection: LDS-staged operands (round-18) -------
__global__ __launch_bounds__(256) void kvall4_k(
    const f16* __restrict__ e16, const f16* __restrict__ win16,
    const float* __restrict__ inb,
    f16* __restrict__ k16all, f16* __restrict__ vt16all,
    f16* __restrict__ v16all) {
  __shared__ __align__(16) f16 Xl[64 * 256];
  __shared__ __align__(16) f16 Wl[64 * 256];
  const int tid = threadIdx.x;
  const int lane = tid & 63, wid = tid >> 6;
  const int la = lane & 31, hi = lane >> 5;
  const int wm = wid & 1, wn = wid >> 1;
  const int bid = blockIdx.x;
  const int l = bid >> 10;
  const int tt = bid & 1023;
  const int bx = tt & 127, by = tt >> 7;  // by 0-3: K cols, 4-7: V cols
  const int e0 = bx * 64, n0 = by * 64;
  const f16* W = win16 + (size_t)l * 3 * kD * kD + (size_t)kD * kD;
  const float* bias = inb + (size_t)l * 3 * kD + kD;

  f16x8 xst[8], wst[8];
#pragma unroll
  for (int p = 0; p < 8; ++p) {
    int id = p * 256 + tid;
    int row = id >> 5, s = id & 31;
    xst[p] = *(const f16x8*)(e16 + (size_t)(e0 + row) * kD + 8 * (s ^ (row & 7)));
    wst[p] = *(const f16x8*)(W + (size_t)(n0 + row) * kD + 8 * (s ^ (row & 7)));
  }
#pragma unroll
  for (int p = 0; p < 8; ++p) {
    int id = p * 256 + tid;
    *(f16x8*)&Xl[8 * id] = xst[p];
    *(f16x8*)&Wl[8 * id] = wst[p];
  }
  __syncthreads();

  const int xrow = wm * 32 + la, wrow = wn * 32 + la;
  f16x8 wr[16], xr[16];
#pragma unroll
  for (int t = 0; t < 16; ++t) {
    xr[t] = *(const f16x8*)&Xl[xrow * 256 + 8 * ((2 * t + hi) ^ (xrow & 7))];
    wr[t] = *(const f16x8*)&Wl[wrow * 256 + 8 * ((2 * t + hi) ^ (wrow & 7))];
  }

  const int m0 = e0 + wm * 32;
  const int nb = n0 + wn * 32;
  if (by < 4) {
    f32x16 acc = {};
#pragma unroll
    for (int t = 0; t < 16; ++t) acc = MFMA32_F16(wr[t], xr[t], acc, 0, 0, 0);
#pragma unroll
    for (int i = 0; i < 16; ++i)
      acc[i] += bias[nb + (i & 3) + 8 * (i >> 2) + 4 * hi];
    store16(acc, k16all + (size_t)l * kS * kD + (size_t)(m0 + la) * kD + nb,
            hi);
  } else {
    f32x16 arm = {}, atr = {};
#pragma unroll
    for (int t = 0; t < 16; ++t) {
      arm = MFMA32_F16(wr[t], xr[t], arm, 0, 0, 0);
      atr = MFMA32_F16(xr[t], wr[t], atr, 0, 0, 0);
    }
    const int dv0 = nb - 256;
#pragma unroll
    for (int i = 0; i < 16; ++i)
      arm[i] += bias[nb + (i & 3) + 8 * (i >> 2) + 4 * hi];
    store16(arm, v16all + (size_t)l * kS * kD + (size_t)(m0 + la) * kD + dv0,
            hi);
    const float bv = bias[nb + la];
#pragma unroll
    for (int i = 0; i < 16; ++i) atr[i] += bv;
    store16(atr, vt16all + (size_t)l * kS * kD + (size_t)(dv0 + la) * kS + m0,
            hi);
  }
}

// ---------- dense attention: round-20-verified (den via MFMA) --------------
__global__ __launch_bounds__(256, 2) void attn_dense7_k(
    const f16* __restrict__ Q, const f16* __restrict__ Km,
    const f16* __restrict__ Vt,
    f16* __restrict__ numOut, float* __restrict__ denOut) {
  __shared__ __align__(16) f16 Kl[2][64 * 128];  // [key][d], XOR-swizzled
  __shared__ __align__(16) f16 Vl[2][128 * 64];  // [d][key], XOR-swizzled
  const int tid = threadIdx.x;
  const int lane = tid & 63, wid = tid >> 6;
  const int la = lane & 31, hi = lane >> 5;
  const int id = blockIdx.x;
  const int grp = id & 15;
  const int h = grp & 1;
  const int z = grp >> 1;
  const int bx = id >> 4;
  const int q0w = bx * 128 + wid * 32;
  const int sb0 = z * (kS / kNS);
  const int nt = (kS / kNS) / 64;  // 16

  f16x8 qb[8];
#pragma unroll
  for (int kk = 0; kk < 8; ++kk)
    qb[kk] = *(const f16x8*)(Q + (size_t)(q0w + la) * kD + h * kDH + kk * 16 +
                             hi * 8);

  int kSrc[4], kDst[4], vSrc[4], vDst[4];
#pragma unroll
  for (int p = 0; p < 4; ++p) {
    int m = wid * 16 + p * 4 + (lane >> 4);
    int s = lane & 15;
    kSrc[p] = (sb0 + m) * kD + h * kDH + 8 * (s ^ (m & 7));
    kDst[p] = m * 128 + 8 * s;
    int cv = p * 256 + tid;
    int d = cv >> 3, sv = cv & 7;
    vSrc[p] = (h * kDH + d) * kS + sb0 + 8 * (sv ^ (d & 7));
    vDst[p] = d * 64 + 8 * sv;
  }

  f32x16 o0 = {}, o1 = {}, o2 = {}, o3 = {}, dacc = {};
  const f16x8 ones = {(f16)1.0f, (f16)1.0f, (f16)1.0f, (f16)1.0f,
                      (f16)1.0f, (f16)1.0f, (f16)1.0f, (f16)1.0f};
  f16x8 kst[4], vst[4];

#pragma unroll
  for (int p = 0; p < 4; ++p) {
    kst[p] = *(const f16x8*)(Km + kSrc[p]);
    vst[p] = *(const f16x8*)(Vt + vSrc[p]);
  }
#pragma unroll
  for (int p = 0; p < 4; ++p) {
    *(f16x8*)&Kl[0][kDst[p]] = kst[p];
    *(f16x8*)&Vl[0][vDst[p]] = vst[p];
  }
  __syncthreads();

  for (int t = 0; t < nt; ++t) {
    const int cur = t & 1;
    if (t + 1 < nt) {
#pragma unroll
      for (int p = 0; p < 4; ++p) {
        kst[p] = *(const f16x8*)(Km + kSrc[p] + (t + 1) * 64 * kD);
        vst[p] = *(const f16x8*)(Vt + vSrc[p] + (t + 1) * 64);
      }
    }

    f32x16 st0 = {}, st1 = {};
    __builtin_amdgcn_s_setprio(1);
#pragma unroll
    for (int kk = 0; kk < 8; ++kk) {
      int sl = 8 * ((kk * 2 + hi) ^ (la & 7));
      f16x8 k0 = *(const f16x8*)&Kl[cur][la * 128 + sl];
      f16x8 k1 = *(const f16x8*)&Kl[cur][(32 + la) * 128 + sl];
      st0 = MFMA32_F16(k0, qb[kk], st0, 0, 0, 0);
      st1 = MFMA32_F16(k1, qb[kk], st1, 0, 0, 0);
    }
    __builtin_amdgcn_s_setprio(0);

    f32x16 pe0, pe1;
#pragma unroll
    for (int i = 0; i < 16; ++i) {
      pe0[i] = __expf(st0[i] * kScale);
      pe1[i] = __expf(st1[i] * kScale);
    }

    f16x8 pf[4];
    pf[0] = build_pfrag(pe0[0], pe0[1], pe0[2], pe0[3], pe0[4], pe0[5], pe0[6], pe0[7]);
    pf[1] = build_pfrag(pe0[8], pe0[9], pe0[10], pe0[11], pe0[12], pe0[13], pe0[14], pe0[15]);
    pf[2] = build_pfrag(pe1[0], pe1[1], pe1[2], pe1[3], pe1[4], pe1[5], pe1[6], pe1[7]);
    pf[3] = build_pfrag(pe1[8], pe1[9], pe1[10], pe1[11], pe1[12], pe1[13], pe1[14], pe1[15]);

    __builtin_amdgcn_s_setprio(1);
#pragma unroll
    for (int dt = 0; dt < 4; ++dt) {
      int d = dt * 32 + la;
      f32x16* op = (dt == 0) ? &o0 : (dt == 1) ? &o1 : (dt == 2) ? &o2 : &o3;
#pragma unroll
      for (int ks = 0; ks < 4; ++ks) {
        f16x8 vf = *(const f16x8*)&Vl[cur][d * 64 + 8 * ((ks * 2 + hi) ^ (d & 7))];
        *op = MFMA32_F16(vf, pf[ks], *op, 0, 0, 0);
      }
    }
#pragma unroll
    for (int ks = 0; ks < 4; ++ks)
      dacc = MFMA32_F16(ones, pf[ks], dacc, 0, 0, 0);
    __builtin_amdgcn_s_setprio(0);

    if (t + 1 < nt) {
      const int nxt = cur ^ 1;
#pragma unroll
      for (int p = 0; p < 4; ++p) {
        *(f16x8*)&Kl[nxt][kDst[p]] = kst[p];
        *(f16x8*)&Vl[nxt][vDst[p]] = vst[p];
      }
      __syncthreads();
    }
  }

  const size_t nbase = ((size_t)z * kH + h) * kL + q0w;
  const size_t rowb = (nbase + la) * kDH;
#pragma unroll
  for (int dt = 0; dt < 4; ++dt) {
    const f32x16* op = (dt == 0) ? &o0 : (dt == 1) ? &o1 : (dt == 2) ? &o2 : &o3;
    store16(*op, numOut + rowb + dt * 32, hi);
  }
  if (lane < 32)
    denOut[((size_t)z * kH + h) * kL + q0w + lane] = dacc[0];
}

// ---------- fused correction + combine; grouped load-prefetch --------------
// Same math as the round-11-verified serial form, but K/V pair loads are
// hoisted into groups of 8 issued ahead of the shfl/exp chains (the chain
// previously began each iteration with a dependent ~200-cyc L2 gather).
__global__ __launch_bounds__(256) void corrcomb_k(
    const unsigned int* __restrict__ loopw, const unsigned char* __restrict__ maskb,
    const int* __restrict__ flags,
    const f16* __restrict__ Q, const f16* __restrict__ Km,
    const f16* __restrict__ V,
    const f16* __restrict__ numb, const float* __restrict__ denb,
    f16* __restrict__ out16) {
  __shared__ float cvL[4][128];
  __shared__ float csL[4];
  const int lane = threadIdx.x & 63;
  const int wid = threadIdx.x >> 6;
  const int w = blockIdx.x * 4 + wid;
  const int f = w >> 1, h = w & 1;
  const int lstride = flags[0];
  const int mstride = flags[1];

  int idx = -1, valid = 0;
  if (lane < 32) {
    idx = (int)loopw[(size_t)(f * 32 + lane) * lstride];
    valid = maskb[(size_t)f * mstride] ? 1 : 0;
  }
#pragma unroll
  for (int j = 0; j < 32; ++j) {
    int oidx = __shfl(idx, j);
    if (lane < 32 && j < lane && oidx == idx) valid = 0;
  }

  const size_t qb = (size_t)f * kD + h * kDH + 2 * lane;
  const float qa = (float)Q[qb];
  const float qbv = (float)Q[qb + 1];
  const size_t lof = (size_t)h * kDH + 2 * lane;
  float s0 = 0.0f, cv0 = 0.0f, cv1 = 0.0f;

  f16x2 kp[8], vp[8];
#pragma unroll
  for (int j = 0; j < 8; ++j) {
    size_t kb = (size_t)__shfl(idx, j) * kD + lof;
    kp[j] = *(const f16x2*)&Km[kb];
    vp[j] = *(const f16x2*)&V[kb];
  }
#pragma unroll
  for (int g = 0; g < 4; ++g) {
    f16x2 kn[8], vn[8];
    if (g < 3) {
#pragma unroll
      for (int j = 0; j < 8; ++j) {
        size_t kb = (size_t)__shfl(idx, (g + 1) * 8 + j) * kD + lof;
        kn[j] = *(const f16x2*)&Km[kb];
        vn[j] = *(const f16x2*)&V[kb];
      }
    }
#pragma unroll
    for (int j = 0; j < 8; ++j) {
      float part = qa * (float)kp[j][0] + qbv * (float)kp[j][1];
#pragma unroll
      for (int m = 1; m < 64; m <<= 1) part += __shfl_xor(part, m);
      if (__shfl(valid, g * 8 + j)) {
        float pe = __expf(part * kScale);
        s0 += pe;
        cv0 += pe * (float)vp[j][0];
        cv1 += pe * (float)vp[j][1];
      }
    }
#pragma unroll
    for (int j = 0; j < 8; ++j) {
      kp[j] = kn[j];
      vp[j] = vn[j];
    }
  }
  cvL[wid][2 * lane] = cv0;
  cvL[wid][2 * lane + 1] = cv1;
  if (lane == 0) csL[wid] = s0;
  __syncthreads();

#pragma unroll
  for (int e = 0; e < 2; ++e) {
    int idx2 = e * 256 + threadIdx.x;
    int floc = idx2 >> 8;
    int c = idx2 & 255;
    int h2 = c >> 7;
    int d = c & 127;
    int widx = floc * 2 + h2;
    int fabs_ = blockIdx.x * 2 + floc;
    float n = -cvL[widx][d];
    float dn = -csL[widx];
#pragma unroll
    for (int z = 0; z < kNS; ++z) {
      n += (float)numb[((size_t)(z * kH + h2) * kL + fabs_) * kDH + d];
      dn += denb[((size_t)z * kH + h2) * kL + fabs_];
    }
    out16[(size_t)fabs_ * kD + h2 * kDH + d] = (f16)(n / dn);
  }
}

extern "C" void kernel_launch(void* const* d_in, const int* in_sizes, int n_in,
                              void* d_out, int out_size, void* d_ws, size_t ws_size,
                              hipStream_t stream) {
  const unsigned int* loopw = (const unsigned int*)d_in[0];
  const unsigned char* fmask = (const unsigned char*)d_in[1];
  const float* edge = (const float*)d_in[2];
  const float* face = (const float*)d_in[3];
  const float* inw = (const float*)d_in[4];
  const float* inb = (const float*)d_in[5];
  const float* outw = (const float*)d_in[6];
  const float* outb = (const float*)d_in[7];
  float* out = (float*)d_out;

  char* p = (char*)d_ws;
  auto alloc = [&](size_t bytes) {
    char* q = p;
    p += (bytes + 255) & ~(size_t)255;
    return q;
  };
  int* flags = (int*)alloc(256);
  f16* e16 = (f16*)alloc((size_t)kS * kD * 2);
  f16* win16 = (f16*)alloc((size_t)kNL * 3 * kD * kD * 2);
  f16* wout16 = (f16*)alloc((size_t)kNL * kD * kD * 2);
  f16* xa = (f16*)alloc((size_t)kL * kD * 2);
  f16* q16 = (f16*)alloc((size_t)kL * kD * 2);
  f16* ao16 = (f16*)alloc((size_t)kL * kD * 2);
  f16* wqo = (f16*)alloc((size_t)3 * kD * kD * 2);
  float* bprime = (float*)alloc((size_t)3 * kD * 4);
  f16* k16all = (f16*)alloc((size_t)kNL * kS * kD * 2);
  f16* vt16all = (f16*)alloc((size_t)kNL * kS * kD * 2);
  f16* v16all = (f16*)alloc((size_t)kNL * kS * kD * 2);
  f16* numb = (f16*)alloc((size_t)kNS * kH * kL * kDH * 2);
  float* denb = (float*)alloc((size_t)kNS * kH * kL * 4);

  prologue_k<<<1793, 256, 0, stream>>>(edge, face, inw, inb, outw, outb,
                                       loopw, fmask, e16, xa, win16, wout16,
                                       flags, wqo, bprime);
  kvall4_k<<<4096, 256, 0, stream>>>(e16, win16, inb, k16all, vt16all, v16all);

  for (int l = 0; l < kNL; ++l) {
    const f16* kl = k16all + (size_t)l * kS * kD;
    const f16* vtl = vt16all + (size_t)l * kS * kD;
    const f16* vl = v16all + (size_t)l * kS * kD;
    if (l == 0) {
      gemm32s_k<<<dim3(64, 4), 256, 0, stream>>>(xa, win16, inb, q16, nullptr);
    } else {
      gemm32s_k<<<dim3(64, 4), 256, 0, stream>>>(
          ao16, wqo + (size_t)(l - 1) * kD * kD, bprime + (l - 1) * kD, q16,
          nullptr);
    }
    attn_dense7_k<<<512, 256, 0, stream>>>(q16, kl, vtl, numb, denb);
    corrcomb_k<<<kL / 2, 256, 0, stream>>>(loopw, fmask, flags, q16, kl, vl,
                                           numb, denb, ao16);
  }
  // final out-projection (only layer 3's survives composition), f32 output
  gemm32s_k<<<dim3(64, 4), 256, 0, stream>>>(
      ao16, wout16 + (size_t)3 * kD * kD, outb + 3 * kD, nullptr, out);
}